// Round 1
// baseline (6107.004 us; speedup 1.0000x reference)
//
#include <hip/hip_runtime.h>
#include <math.h>

// Problem constants: B=2, T=2048, E=1024, H=16, D=64; M = B*T = 4096
#define MM   4096
#define TT   2048
#define EE   1024
#define HH   16
#define DD   64

// ---------------------------------------------------------------- reductions
__device__ __forceinline__ float blockSum256(float v, volatile float* sb) {
    int lane = threadIdx.x & 63, w = threadIdx.x >> 6;
#pragma unroll
    for (int o = 32; o; o >>= 1) v += __shfl_xor(v, o);
    if (lane == 0) sb[w] = v;
    __syncthreads();
    v = sb[0] + sb[1] + sb[2] + sb[3];
    __syncthreads();
    return v;
}

// ---------------------------------------------------------------- block_norm
// out (row, 1025): out[0] = sqrt(exp(curv) + sum(y^2)), out[1+i] = y_i
// y = layer_norm(in[row*ld .. +1024]) * w + b
__global__ __launch_bounds__(256) void block_norm_k(
    const float* __restrict__ in, int ld,
    float* __restrict__ out,
    const float* __restrict__ lw, const float* __restrict__ lb,
    const float* __restrict__ curv)
{
    int row = blockIdx.x;
    const float* x = in + (size_t)row * ld;
    float* o = out + (size_t)row * 1025;
    __shared__ float sb[4];
    int tid = threadIdx.x;
    float v[4]; float s1 = 0.f, s2 = 0.f;
#pragma unroll
    for (int r = 0; r < 4; r++) {
        float t = x[tid + 256 * r];
        v[r] = t; s1 += t; s2 += t * t;
    }
    s1 = blockSum256(s1, sb);
    s2 = blockSum256(s2, sb);
    float mean = s1 * (1.f / 1024.f);
    float var  = s2 * (1.f / 1024.f) - mean * mean;
    float rs = rsqrtf(var + 1e-5f);
    float y[4]; float ssq = 0.f;
#pragma unroll
    for (int r = 0; r < 4; r++) {
        int i = tid + 256 * r;
        float t = (v[r] - mean) * rs * lw[i] + lb[i];
        y[r] = t; ssq += t * t;
    }
    ssq = blockSum256(ssq, sb);
#pragma unroll
    for (int r = 0; r < 4; r++) o[1 + tid + 256 * r] = y[r];
    if (tid == 0) o[0] = sqrtf(expf(*curv) + ssq);
}

// ---------------------------------------------------------------- row x0 project
// buf[row*stride] = sqrt(exp(curv) + sum_{i<n} buf[row*stride+1+i]^2)
__global__ __launch_bounds__(256) void row_x0_k(
    float* __restrict__ buf, int stride, int n, const float* __restrict__ curv)
{
    int row = blockIdx.x;
    float* base = buf + (size_t)row * stride;
    __shared__ float sb[4];
    float s = 0.f;
    for (int i = threadIdx.x; i < n; i += 256) { float t = base[1 + i]; s += t * t; }
    s = blockSum256(s, sb);
    if (threadIdx.x == 0) base[0] = sqrtf(expf(*curv) + s);
}

// ---------------------------------------------------------------- SGEMM (fp32)
// C[m,n] = act( A[m,:]@Bw[:,n] + bias[n] ) + skip[m,n]
// BM=BN=64, BK=16, 256 threads, 4x4 per thread. M assumed multiple of 64.
template<bool BIAS, bool GELU, bool SKIP>
__global__ __launch_bounds__(256) void sgemm_k(
    const float* __restrict__ A, int lda,
    const float* __restrict__ Bw, int ldb,
    const float* __restrict__ bias,
    const float* __restrict__ skip, int ldskip,
    float* __restrict__ C, int ldc,
    int N, int K)
{
    __shared__ float As[16][64];
    __shared__ float Bs[16][64];
    int tid = threadIdx.x;
    int tx = tid & 15, ty = tid >> 4;
    int m0 = blockIdx.y * 64, n0 = blockIdx.x * 64;
    float acc[4][4] = {};
    int aK = tid & 15, aM = tid >> 4;   // A tile loader coords
    int bN = tid & 63, bK = tid >> 6;   // B tile loader coords
    for (int k0 = 0; k0 < K; k0 += 16) {
#pragma unroll
        for (int r = 0; r < 4; r++) {
            int m = aM + 16 * r; int kk = k0 + aK;
            As[aK][m] = (kk < K) ? A[(size_t)(m0 + m) * lda + kk] : 0.f;
        }
#pragma unroll
        for (int r = 0; r < 4; r++) {
            int kk = k0 + bK + 4 * r; int n = n0 + bN;
            Bs[bK + 4 * r][bN] = (kk < K && n < N) ? Bw[(size_t)kk * ldb + n] : 0.f;
        }
        __syncthreads();
#pragma unroll
        for (int k = 0; k < 16; k++) {
            float4 a4 = *(const float4*)&As[k][ty * 4];
            float4 b4 = *(const float4*)&Bs[k][tx * 4];
            float av[4] = {a4.x, a4.y, a4.z, a4.w};
            float bv[4] = {b4.x, b4.y, b4.z, b4.w};
#pragma unroll
            for (int i = 0; i < 4; i++)
#pragma unroll
                for (int j = 0; j < 4; j++) acc[i][j] += av[i] * bv[j];
        }
        __syncthreads();
    }
#pragma unroll
    for (int i = 0; i < 4; i++) {
        int m = m0 + ty * 4 + i;
#pragma unroll
        for (int j = 0; j < 4; j++) {
            int n = n0 + tx * 4 + j;
            if (n < N) {
                float v = acc[i][j];
                if (BIAS) v += bias[n];
                if (GELU) v = 0.5f * v * (1.f + erff(v * 0.70710678118654752f));
                if (SKIP) v += skip[(size_t)m * ldskip + n];
                C[(size_t)m * ldc + n] = v;
            }
        }
    }
}

// ---------------------------------------------------------------- RoPE + split
// QKV: (M, 3072) token rows [q|k|v], each (H,D). Writes head-major (B*H, T, D)
// q,k (roped), v (raw), plus qt/kt/vt = sqrt(Kh + |.|^2).
__global__ __launch_bounds__(256) void rope_k(
    const float* __restrict__ QKV, const float* __restrict__ curv,
    float* __restrict__ Qo, float* __restrict__ Ko, float* __restrict__ Vo,
    float* __restrict__ qt, float* __restrict__ kt, float* __restrict__ vt)
{
    int row = blockIdx.x;              // b*T + t
    int b = row >> 11, t = row & (TT - 1);
    int wv = threadIdx.x >> 6, d = threadIdx.x & 63;
    int j = d & 31;
    float fr = (float)t * powf(10000.0f, -(float)(2 * j) / 64.0f);
    float cv = cosf(fr), sv = sinf(fr);
    float sgn = (d < 32) ? sv : -sv;
    for (int h = wv; h < HH; h += 4) {
        float Kh = expf(curv[h]);
        const float* base = QKV + (size_t)row * 3072 + h * 64;
        float q = base[d], k = base[1024 + d], v = base[2048 + d];
        float qp = __shfl_xor(q, 32);
        float kp = __shfl_xor(k, 32);
        float qr = q * cv + qp * sgn;
        float kr = k * cv + kp * sgn;
        float sq = qr * qr, sk = kr * kr, sv2 = v * v;
#pragma unroll
        for (int o = 32; o; o >>= 1) {
            sq  += __shfl_xor(sq, o);
            sk  += __shfl_xor(sk, o);
            sv2 += __shfl_xor(sv2, o);
        }
        size_t oidx = ((size_t)(b * HH + h) * TT + t);
        Qo[oidx * 64 + d] = qr;
        Ko[oidx * 64 + d] = kr;
        Vo[oidx * 64 + d] = v;
        if (d == 0) {
            qt[oidx] = sqrtf(Kh + sq);
            kt[oidx] = sqrtf(Kh + sk);
            vt[oidx] = sqrtf(Kh + sv2);
        }
    }
}

// ---------------------------------------------------------------- flash hyperbolic attention
// One block = (b,h) x 32-query tile; online softmax over s-tiles of 64.
// logit(t,s) = -sqrt(Kh)*arccosh(max(-(q.k - qt*kt)/Kh, 1+1e-7)), causal.
// O (M,1040): col h*65 + e, o normalized by Lorentz norm: o *= sqrt(Kh)/hn.
#define FT_TQ 32
#define FT_TS 64
__global__ __launch_bounds__(256) void flash_k(
    const float* __restrict__ Q, const float* __restrict__ Km,
    const float* __restrict__ Vm,
    const float* __restrict__ qt, const float* __restrict__ kt,
    const float* __restrict__ vt,
    const float* __restrict__ curv,
    float* __restrict__ O)
{
    int bh = blockIdx.y; int h = bh & (HH - 1); int b = bh >> 4;
    int qbase = blockIdx.x * FT_TQ;
    float Kh = expf(curv[h]); float sqKh = sqrtf(Kh);
    const float* Qp  = Q  + (size_t)bh * TT * 64;
    const float* Kp  = Km + (size_t)bh * TT * 64;
    const float* Vp  = Vm + (size_t)bh * TT * 64;
    const float* qtp = qt + (size_t)bh * TT;
    const float* ktp = kt + (size_t)bh * TT;
    const float* vtp = vt + (size_t)bh * TT;

    __shared__ float sQ[FT_TQ][65];
    __shared__ float sK[FT_TS][65];
    __shared__ float sLV[FT_TS][66];   // col 0 = vt, 1..64 = v
    __shared__ float sP[FT_TQ][65];
    __shared__ float sQt[FT_TQ], sKt[FT_TS], sM[FT_TQ], sL[FT_TQ], sAl[FT_TQ];

    int tid = threadIdx.x;
    for (int idx = tid; idx < FT_TQ * 64; idx += 256) {
        int q = idx >> 6, d = idx & 63;
        sQ[q][d] = Qp[(size_t)(qbase + q) * 64 + d];
    }
    if (tid < FT_TQ) { sQt[tid] = qtp[qbase + tid]; sM[tid] = -INFINITY; sL[tid] = 0.f; }

    int eg = tid & 7, otq = tid >> 3;     // phase-B ownership: query otq, dims eg*8..
    float accO[9];
#pragma unroll
    for (int j = 0; j < 9; j++) accO[j] = 0.f;
    int wv = tid >> 6, lane = tid & 63;
    int tx = tid & 15, ty = tid >> 4;
    int send = qbase + FT_TQ;

    for (int sb = 0; sb < send; sb += FT_TS) {
        __syncthreads();
        for (int idx = tid; idx < FT_TS * 64; idx += 256) {
            int s = idx >> 6, d = idx & 63;
            sK[s][d]      = Kp[(size_t)(sb + s) * 64 + d];
            sLV[s][1 + d] = Vp[(size_t)(sb + s) * 64 + d];
        }
        if (tid < FT_TS) { sKt[tid] = ktp[sb + tid]; sLV[tid][0] = vtp[sb + tid]; }
        __syncthreads();

        // phase A: raw logits -> sP
#pragma unroll
        for (int i = 0; i < 2; i++) {
            int tq = ty * 2 + i; int tg = qbase + tq;
            float qtv = sQt[tq];
            float dots[4] = {0.f, 0.f, 0.f, 0.f};
            for (int d = 0; d < 64; d++) {
                float qv = sQ[tq][d];
#pragma unroll
                for (int jj = 0; jj < 4; jj++) dots[jj] += qv * sK[tx * 4 + jj][d];
            }
#pragma unroll
            for (int jj = 0; jj < 4; jj++) {
                int s = tx * 4 + jj; int sg = sb + s;
                float logit;
                if (sg > tg) logit = -INFINITY;
                else {
                    float inner = dots[jj] - qtv * sKt[s];
                    float ratio = fmaxf(-inner / Kh, 1.0f + 1e-7f);
                    logit = -sqKh * acoshf(ratio);
                }
                sP[tq][s] = logit;
            }
        }
        __syncthreads();

        // phase A2: online-softmax update, one wave owns 8 queries
#pragma unroll
        for (int q8 = 0; q8 < 8; q8++) {
            int tq = wv * 8 + q8;
            float lg = sP[tq][lane];
            float mx = lg;
#pragma unroll
            for (int o = 32; o; o >>= 1) mx = fmaxf(mx, __shfl_xor(mx, o));
            float mo = sM[tq];
            float mn = fmaxf(mo, mx);
            float p = __expf(lg - mn);
            float sm = p;
#pragma unroll
            for (int o = 32; o; o >>= 1) sm += __shfl_xor(sm, o);
            sP[tq][lane] = p;
            if (lane == 0) {
                float al = __expf(mo - mn);
                sAl[tq] = al;
                sL[tq] = sL[tq] * al + sm;
                sM[tq] = mn;
            }
        }
        __syncthreads();

        // phase B: acc = acc*alpha + P @ LV
        float al = sAl[otq];
#pragma unroll
        for (int j = 0; j < 9; j++) accO[j] *= al;
        for (int s = 0; s < FT_TS; s++) {
            float p = sP[otq][s];
#pragma unroll
            for (int j = 0; j < 8; j++) accO[j] += p * sLV[s][eg * 8 + j];
            if (eg == 7) accO[8] += p * sLV[s][64];
        }
    }
    __syncthreads();

    // epilogue: o = acc/l, Lorentz normalize, write token-major (M,1040)
    float inv = 1.0f / sL[otq];
#pragma unroll
    for (int j = 0; j < 9; j++) accO[j] *= inv;
    float part = 0.f;
#pragma unroll
    for (int j = 0; j < 8; j++) { int e = eg * 8 + j; if (e >= 1) part += accO[j] * accO[j]; }
    if (eg == 7) part += accO[8] * accO[8];
    sP[otq][eg] = part;
    __syncthreads();
    if (eg == 0) {
        float ssum = 0.f;
#pragma unroll
        for (int r = 0; r < 8; r++) ssum += sP[otq][r];
        float o0 = accO[0];
        float ln2 = o0 * o0 - ssum;
        float hn = sqrtf(fmaxf(ln2, 1e-12f));
        sP[otq][8] = sqKh / hn;
    }
    __syncthreads();
    float scale = sP[otq][8];
    size_t orow = (size_t)(b * TT + qbase + otq) * 1040 + h * 65;
#pragma unroll
    for (int j = 0; j < 8; j++) O[orow + eg * 8 + j] = accO[j] * scale;
    if (eg == 7) O[orow + 64] = accO[8] * scale;
}

// ---------------------------------------------------------------- launch
extern "C" void kernel_launch(void* const* d_in, const int* in_sizes, int n_in,
                              void* d_out, int out_size, void* d_ws, size_t ws_size,
                              hipStream_t stream) {
    const float* x    = (const float*)d_in[0];
    const float* bc   = (const float*)d_in[1];
    const float* mc   = (const float*)d_in[2];
    const float* ac   = (const float*)d_in[3];
    const float* w_qkv = (const float*)d_in[4];
    const float* w_ap  = (const float*)d_in[5];
    const float* b_ap  = (const float*)d_in[6];
    const float* w_me  = (const float*)d_in[7];
    const float* b_me  = (const float*)d_in[8];
    const float* w_ms  = (const float*)d_in[9];
    const float* b_ms  = (const float*)d_in[10];
    const float* lnw  = (const float*)d_in[11];
    const float* lnb  = (const float*)d_in[12];
    float* out = (float*)d_out;
    float* ws  = (float*)d_ws;

    const size_t M = MM;
    // workspace layout (floats), with deliberate aliasing (all uses are
    // strictly stream-ordered; see per-launch comments):
    float* X2 = ws;                          // M*1024: lx2[...,1:]; earlier aliased as Dk
    float* Bb = X2 + M * 1024;               // M*1025: ln output; earlier aliased as Dq
    float* C  = Bb + M * 1025;               // M*4100: qkv -> o_t -> mlp hidden
    float* Qt = C + M * 4100;                // 65536
    float* Kt = Qt + (size_t)2 * HH * TT;    // 65536
    float* Vt = Kt + (size_t)2 * HH * TT;    // 65536
    float* Dq = Bb;                          // M*1024 (fits in M*1025 region)
    float* Dk = X2;                          // M*1024
    float* Dv = C + M * 3072;                // v lives in qkv-scratch tail

    // 1. ln1 = block_norm(project(x)) — lx1[...,1:] == x, read x directly
    block_norm_k<<<MM, 256, 0, stream>>>(x, 1024, Bb, lnw, lnb, bc);
    // 2. qkv = ln1 @ w_qkv   (M,1025)x(1025,3072) -> C
    sgemm_k<false, false, false><<<dim3(48, 64), 256, 0, stream>>>(
        Bb, 1025, w_qkv, 3072, nullptr, nullptr, 0, C, 3072, 3072, 1025);
    // 3. RoPE + split + row norms (reads C head, writes Dq=Bb, Dk=X2, Dv=C tail)
    rope_k<<<MM, 256, 0, stream>>>(C, ac, Dq, Dk, Dv, Qt, Kt, Vt);
    // 4. attention -> o_t (M,1040) into C head (disjoint from Dv tail)
    flash_k<<<dim3(TT / FT_TQ, 2 * HH), 256, 0, stream>>>(Dq, Dk, Dv, Qt, Kt, Vt, ac, C);
    // 5. lx2[...,1:] = x + o_t @ w_attn_proj + b   -> X2 (overwrites Dk: flash done)
    sgemm_k<true, false, true><<<dim3(16, 64), 256, 0, stream>>>(
        C, 1040, w_ap, 1024, b_ap, x, 1024, X2, 1024, 1024, 1040);
    // 6. ln2 = block_norm(lx2) -> Bb (overwrites Dq: flash done)
    block_norm_k<<<MM, 256, 0, stream>>>(X2, 1024, Bb, lnw, lnb, bc);
    // 7. h = gelu(ln2 @ w_mlp_expand + b) -> C cols 1..4099 (overwrites o_t & Dv)
    sgemm_k<true, true, false><<<dim3(65, 64), 256, 0, stream>>>(
        Bb, 1025, w_me, 4099, b_me, nullptr, 0, C + 1, 4100, 4099, 1025);
    // 8. h x0 column: C[:,0] = sqrt(exp(mlp_curv) + sum h^2)
    row_x0_k<<<MM, 256, 0, stream>>>(C, 4100, 4099, mc);
    // 9. out[...,1:] = lx2[...,1:] + h @ w_mlp_shrink + b   (K=4100)
    sgemm_k<true, false, true><<<dim3(16, 64), 256, 0, stream>>>(
        C, 4100, w_ms, 1024, b_ms, X2, 1024, out + 1, 1025, 1024, 4100);
    // 10. out[...,0] = sqrt(exp(block_curv) + sum out[...,1:]^2)
    row_x0_k<<<MM, 256, 0, stream>>>(out, 1025, 1024, bc);
}

// Round 3
// 2997.014 us; speedup vs baseline: 2.0377x; 2.0377x over previous
//
#include <hip/hip_runtime.h>
#include <math.h>

// Problem constants: B=2, T=2048, E=1024, H=16, D=64; M = B*T = 4096
#define MM   4096
#define TT   2048
#define EE   1024
#define HH   16
#define DD   64

// ---------------------------------------------------------------- reductions
__device__ __forceinline__ float blockSum256(float v, volatile float* sb) {
    int lane = threadIdx.x & 63, w = threadIdx.x >> 6;
#pragma unroll
    for (int o = 32; o; o >>= 1) v += __shfl_xor(v, o);
    if (lane == 0) sb[w] = v;
    __syncthreads();
    v = sb[0] + sb[1] + sb[2] + sb[3];
    __syncthreads();
    return v;
}

// ---------------------------------------------------------------- block_norm
__global__ __launch_bounds__(256) void block_norm_k(
    const float* __restrict__ in, int ld,
    float* __restrict__ out,
    const float* __restrict__ lw, const float* __restrict__ lb,
    const float* __restrict__ curv)
{
    int row = blockIdx.x;
    const float* x = in + (size_t)row * ld;
    float* o = out + (size_t)row * 1025;
    __shared__ float sb[4];
    int tid = threadIdx.x;
    float v[4]; float s1 = 0.f, s2 = 0.f;
#pragma unroll
    for (int r = 0; r < 4; r++) {
        float t = x[tid + 256 * r];
        v[r] = t; s1 += t; s2 += t * t;
    }
    s1 = blockSum256(s1, sb);
    s2 = blockSum256(s2, sb);
    float mean = s1 * (1.f / 1024.f);
    float var  = s2 * (1.f / 1024.f) - mean * mean;
    float rs = rsqrtf(var + 1e-5f);
    float y[4]; float ssq = 0.f;
#pragma unroll
    for (int r = 0; r < 4; r++) {
        int i = tid + 256 * r;
        float t = (v[r] - mean) * rs * lw[i] + lb[i];
        y[r] = t; ssq += t * t;
    }
    ssq = blockSum256(ssq, sb);
#pragma unroll
    for (int r = 0; r < 4; r++) o[1 + tid + 256 * r] = y[r];
    if (tid == 0) o[0] = sqrtf(expf(*curv) + ssq);
}

// ---------------------------------------------------------------- row x0 project
__global__ __launch_bounds__(256) void row_x0_k(
    float* __restrict__ buf, int stride, int n, const float* __restrict__ curv)
{
    int row = blockIdx.x;
    float* base = buf + (size_t)row * stride;
    __shared__ float sb[4];
    float s = 0.f;
    for (int i = threadIdx.x; i < n; i += 256) { float t = base[1 + i]; s += t * t; }
    s = blockSum256(s, sb);
    if (threadIdx.x == 0) base[0] = sqrtf(expf(*curv) + s);
}

// ---------------------------------------------------------------- SGEMM (fp32)
template<bool BIAS, bool GELU, bool SKIP>
__global__ __launch_bounds__(256) void sgemm_k(
    const float* __restrict__ A, int lda,
    const float* __restrict__ Bw, int ldb,
    const float* __restrict__ bias,
    const float* __restrict__ skip, int ldskip,
    float* __restrict__ C, int ldc,
    int N, int K)
{
    __shared__ float As[16][64];
    __shared__ float Bs[16][64];
    int tid = threadIdx.x;
    int tx = tid & 15, ty = tid >> 4;
    int m0 = blockIdx.y * 64, n0 = blockIdx.x * 64;
    float acc[4][4] = {};
    int aK = tid & 15, aM = tid >> 4;
    int bN = tid & 63, bK = tid >> 6;
    for (int k0 = 0; k0 < K; k0 += 16) {
#pragma unroll
        for (int r = 0; r < 4; r++) {
            int m = aM + 16 * r; int kk = k0 + aK;
            As[aK][m] = (kk < K) ? A[(size_t)(m0 + m) * lda + kk] : 0.f;
        }
#pragma unroll
        for (int r = 0; r < 4; r++) {
            int kk = k0 + bK + 4 * r; int n = n0 + bN;
            Bs[bK + 4 * r][bN] = (kk < K && n < N) ? Bw[(size_t)kk * ldb + n] : 0.f;
        }
        __syncthreads();
#pragma unroll
        for (int k = 0; k < 16; k++) {
            float4 a4 = *(const float4*)&As[k][ty * 4];
            float4 b4 = *(const float4*)&Bs[k][tx * 4];
            float av[4] = {a4.x, a4.y, a4.z, a4.w};
            float bv[4] = {b4.x, b4.y, b4.z, b4.w};
#pragma unroll
            for (int i = 0; i < 4; i++)
#pragma unroll
                for (int j = 0; j < 4; j++) acc[i][j] += av[i] * bv[j];
        }
        __syncthreads();
    }
#pragma unroll
    for (int i = 0; i < 4; i++) {
        int m = m0 + ty * 4 + i;
#pragma unroll
        for (int j = 0; j < 4; j++) {
            int n = n0 + tx * 4 + j;
            if (n < N) {
                float v = acc[i][j];
                if (BIAS) v += bias[n];
                if (GELU) v = 0.5f * v * (1.f + erff(v * 0.70710678118654752f));
                if (SKIP) v += skip[(size_t)m * ldskip + n];
                C[(size_t)m * ldc + n] = v;
            }
        }
    }
}

// ---------------------------------------------------------------- RoPE + split
__global__ __launch_bounds__(256) void rope_k(
    const float* __restrict__ QKV, const float* __restrict__ curv,
    float* __restrict__ Qo, float* __restrict__ Ko, float* __restrict__ Vo,
    float* __restrict__ qt, float* __restrict__ kt, float* __restrict__ vt)
{
    int row = blockIdx.x;              // b*T + t
    int b = row >> 11, t = row & (TT - 1);
    int wv = threadIdx.x >> 6, d = threadIdx.x & 63;
    int j = d & 31;
    float fr = (float)t * powf(10000.0f, -(float)(2 * j) / 64.0f);
    float cv = cosf(fr), sv = sinf(fr);
    float sgn = (d < 32) ? sv : -sv;
    for (int h = wv; h < HH; h += 4) {
        float Kh = expf(curv[h]);
        const float* base = QKV + (size_t)row * 3072 + h * 64;
        float q = base[d], k = base[1024 + d], v = base[2048 + d];
        float qp = __shfl_xor(q, 32);
        float kp = __shfl_xor(k, 32);
        float qr = q * cv + qp * sgn;
        float kr = k * cv + kp * sgn;
        float sq = qr * qr, sk = kr * kr, sv2 = v * v;
#pragma unroll
        for (int o = 32; o; o >>= 1) {
            sq  += __shfl_xor(sq, o);
            sk  += __shfl_xor(sk, o);
            sv2 += __shfl_xor(sv2, o);
        }
        size_t oidx = ((size_t)(b * HH + h) * TT + t);
        Qo[oidx * 64 + d] = qr;
        Ko[oidx * 64 + d] = kr;
        Vo[oidx * 64 + d] = v;
        if (d == 0) {
            qt[oidx] = sqrtf(Kh + sq);
            kt[oidx] = sqrtf(Kh + sk);
            vt[oidx] = sqrtf(Kh + sv2);
        }
    }
}

// ---------------------------------------------------------------- flash hyperbolic attention (v2)
// Register-resident: thread owns 2 queries x 16 dims (4 lanes/query).
// No max-tracking (logits <= 0, diagonal ~0 always present): p = exp(logit).
// Q in regs; K,V staged in LDS stride 64 (broadcast reads, <=2-way banks).
// Dots reduced via 3-shuffle transpose-reduce; p shared via 3 shuffles.
#define FT_TQ 128
#define FT_TS 64
__global__ __launch_bounds__(256, 4) void flash_k(
    const float* __restrict__ Q, const float* __restrict__ Km,
    const float* __restrict__ Vm,
    const float* __restrict__ qt, const float* __restrict__ kt,
    const float* __restrict__ vt,
    const float* __restrict__ curv,
    float* __restrict__ O)
{
    __shared__ float sK[FT_TS * 64];
    __shared__ float sV[FT_TS * 64];
    __shared__ float skt[FT_TS];
    __shared__ float svt[FT_TS];

    int bh = blockIdx.y; int h = bh & (HH - 1); int b = bh >> 4;
    int qbase = ((int)gridDim.x - 1 - (int)blockIdx.x) * FT_TQ;  // longest blocks first
    float Kh = expf(curv[h]); float sqKh = sqrtf(Kh);
    float negInvKh = -1.0f / Kh;
    const float* Qp  = Q  + (size_t)bh * TT * 64;
    const float* Kp  = Km + (size_t)bh * TT * 64;
    const float* Vp  = Vm + (size_t)bh * TT * 64;
    const float* qtp = qt + (size_t)bh * TT;
    const float* ktp = kt + (size_t)bh * TT;
    const float* vtp = vt + (size_t)bh * TT;

    int tid = threadIdx.x;
    int g = tid & 3, qp = tid >> 2;      // 4 lanes per query-pair
    int q0 = qbase + qp * 2;
    bool g1 = (g & 1), g2b = (g & 2);

    float qreg[2][16];
    float qtv[2];
#pragma unroll
    for (int i = 0; i < 2; i++) {
        const float* qrow = Qp + (size_t)(q0 + i) * 64 + g * 16;
#pragma unroll
        for (int j = 0; j < 16; j += 4) {
            float4 f = *(const float4*)(qrow + j);
            qreg[i][j] = f.x; qreg[i][j + 1] = f.y; qreg[i][j + 2] = f.z; qreg[i][j + 3] = f.w;
        }
        qtv[i] = qtp[q0 + i];
    }
    float acc[2][16] = {};
    float acc0[2] = {0.f, 0.f};
    float lsum[2] = {0.f, 0.f};

    int send = qbase + FT_TQ;
    for (int sb = 0; sb < send; sb += FT_TS) {
        __syncthreads();
#pragma unroll
        for (int r = 0; r < 4; r++) {
            int idx = tid + 256 * r;            // float4 index, 0..1023
            int row = idx >> 4, col = (idx & 15) * 4;
            *(float4*)&sK[row * 64 + col] = *(const float4*)&Kp[(size_t)(sb + row) * 64 + col];
            *(float4*)&sV[row * 64 + col] = *(const float4*)&Vp[(size_t)(sb + row) * 64 + col];
        }
        if (tid < FT_TS) skt[tid] = ktp[sb + tid];
        else if (tid < 2 * FT_TS) svt[tid - FT_TS] = vtp[sb + tid - FT_TS];
        __syncthreads();

        for (int s0 = 0; s0 < FT_TS; s0 += 4) {
            // partial dots over own 16 dims, 4 s-cols x 2 queries
            float part[2][4] = {};
#pragma unroll
            for (int jj = 0; jj < 4; jj++) {
                const float* kcol = &sK[(s0 + jj) * 64 + g * 16];
#pragma unroll
                for (int d = 0; d < 16; d += 4) {
                    float4 kv = *(const float4*)(kcol + d);
                    part[0][jj] += qreg[0][d] * kv.x + qreg[0][d + 1] * kv.y
                                 + qreg[0][d + 2] * kv.z + qreg[0][d + 3] * kv.w;
                    part[1][jj] += qreg[1][d] * kv.x + qreg[1][d + 1] * kv.y
                                 + qreg[1][d + 2] * kv.z + qreg[1][d + 3] * kv.w;
                }
            }
            // transpose-reduce across the 4-lane group: lane g ends with dot for col g
            float own[2];
#pragma unroll
            for (int i = 0; i < 2; i++) {
                float y0 = g1 ? part[i][1] : part[i][0];
                float z0 = g1 ? part[i][0] : part[i][1];
                float y1 = g1 ? part[i][3] : part[i][2];
                float z1 = g1 ? part[i][2] : part[i][3];
                float r0 = y0 + __shfl_xor(z0, 1);
                float r1 = y1 + __shfl_xor(z1, 1);
                float u = g2b ? r1 : r0;
                float w = g2b ? r0 : r1;
                own[i] = u + __shfl_xor(w, 2);
            }
            // logit -> p for own s-col
            int scol = sb + s0 + g;
            float ktv = skt[s0 + g];
            float pown[2];
#pragma unroll
            for (int i = 0; i < 2; i++) {
                float inner = own[i] - qtv[i] * ktv;
                float ratio = fmaxf(inner * negInvKh, 1.0f + 1e-7f);
                float y = ratio + sqrtf(ratio * ratio - 1.0f);
                float pv = exp2f(-sqKh * log2f(y));   // exp(-sqKh*ln y) in base 2
                pown[i] = (scol <= q0 + i) ? pv : 0.f;
            }
            // share p: pa[i][m] corresponds to s-col (g^m)
            float pa[2][4];
#pragma unroll
            for (int i = 0; i < 2; i++) {
                pa[i][0] = pown[i];
                pa[i][1] = __shfl_xor(pown[i], 1);
                pa[i][2] = __shfl_xor(pown[i], 2);
                pa[i][3] = __shfl_xor(pa[i][1], 2);
                lsum[i] += (pa[i][0] + pa[i][1]) + (pa[i][2] + pa[i][3]);
            }
            // PV accumulate (V rows read in g^m order)
#pragma unroll
            for (int m = 0; m < 4; m++) {
                int srow = s0 + (g ^ m);
                const float* vrow = &sV[srow * 64 + g * 16];
                float vtvv = svt[srow];
                acc0[0] += pa[0][m] * vtvv;
                acc0[1] += pa[1][m] * vtvv;
#pragma unroll
                for (int d = 0; d < 16; d += 4) {
                    float4 vv = *(const float4*)(vrow + d);
                    acc[0][d]     += pa[0][m] * vv.x;
                    acc[0][d + 1] += pa[0][m] * vv.y;
                    acc[0][d + 2] += pa[0][m] * vv.z;
                    acc[0][d + 3] += pa[0][m] * vv.w;
                    acc[1][d]     += pa[1][m] * vv.x;
                    acc[1][d + 1] += pa[1][m] * vv.y;
                    acc[1][d + 2] += pa[1][m] * vv.z;
                    acc[1][d + 3] += pa[1][m] * vv.w;
                }
            }
        }
    }

    // epilogue: normalize, Lorentz-scale, write token-major (M,1040)
#pragma unroll
    for (int i = 0; i < 2; i++) {
        float inv = 1.0f / lsum[i];
        float o0 = acc0[i] * inv;
        float prt = 0.f;
#pragma unroll
        for (int j = 0; j < 16; j++) { float t = acc[i][j] * inv; acc[i][j] = t; prt += t * t; }
        prt += __shfl_xor(prt, 1);
        prt += __shfl_xor(prt, 2);
        float ln2v = o0 * o0 - prt;
        float scale = sqKh * rsqrtf(fmaxf(ln2v, 1e-12f));
        size_t orow = (size_t)(b * TT + q0 + i) * 1040 + h * 65;
        if (g == 0) O[orow] = o0 * scale;
#pragma unroll
        for (int j = 0; j < 16; j++) O[orow + 1 + g * 16 + j] = acc[i][j] * scale;
    }
}

// ---------------------------------------------------------------- launch
extern "C" void kernel_launch(void* const* d_in, const int* in_sizes, int n_in,
                              void* d_out, int out_size, void* d_ws, size_t ws_size,
                              hipStream_t stream) {
    const float* x    = (const float*)d_in[0];
    const float* bc   = (const float*)d_in[1];
    const float* mc   = (const float*)d_in[2];
    const float* ac   = (const float*)d_in[3];
    const float* w_qkv = (const float*)d_in[4];
    const float* w_ap  = (const float*)d_in[5];
    const float* b_ap  = (const float*)d_in[6];
    const float* w_me  = (const float*)d_in[7];
    const float* b_me  = (const float*)d_in[8];
    const float* w_ms  = (const float*)d_in[9];
    const float* b_ms  = (const float*)d_in[10];
    const float* lnw  = (const float*)d_in[11];
    const float* lnb  = (const float*)d_in[12];
    float* out = (float*)d_out;
    float* ws  = (float*)d_ws;

    const size_t M = MM;
    float* X2 = ws;                          // M*1024: lx2[...,1:]; earlier aliased as Dk
    float* Bb = X2 + M * 1024;               // M*1025: ln output; earlier aliased as Dq
    float* C  = Bb + M * 1025;               // M*4100: qkv -> o_t -> mlp hidden
    float* Qt = C + M * 4100;                // 65536
    float* Kt = Qt + (size_t)2 * HH * TT;    // 65536
    float* Vt = Kt + (size_t)2 * HH * TT;    // 65536
    float* Dq = Bb;
    float* Dk = X2;
    float* Dv = C + M * 3072;

    // 1. ln1 = block_norm(project(x)) — lx1[...,1:] == x
    block_norm_k<<<MM, 256, 0, stream>>>(x, 1024, Bb, lnw, lnb, bc);
    // 2. qkv = ln1 @ w_qkv
    sgemm_k<false, false, false><<<dim3(48, 64), 256, 0, stream>>>(
        Bb, 1025, w_qkv, 3072, nullptr, nullptr, 0, C, 3072, 3072, 1025);
    // 3. RoPE + split + row norms
    rope_k<<<MM, 256, 0, stream>>>(C, ac, Dq, Dk, Dv, Qt, Kt, Vt);
    // 4. attention -> o_t (M,1040) into C head
    flash_k<<<dim3(TT / FT_TQ, 2 * HH), 256, 0, stream>>>(Dq, Dk, Dv, Qt, Kt, Vt, ac, C);
    // 5. lx2[...,1:] = x + o_t @ w_attn_proj + b
    sgemm_k<true, false, true><<<dim3(16, 64), 256, 0, stream>>>(
        C, 1040, w_ap, 1024, b_ap, x, 1024, X2, 1024, 1024, 1040);
    // 6. ln2 = block_norm(lx2)
    block_norm_k<<<MM, 256, 0, stream>>>(X2, 1024, Bb, lnw, lnb, bc);
    // 7. h = gelu(ln2 @ w_mlp_expand + b)
    sgemm_k<true, true, false><<<dim3(65, 64), 256, 0, stream>>>(
        Bb, 1025, w_me, 4099, b_me, nullptr, 0, C + 1, 4100, 4099, 1025);
    // 8. h x0 column
    row_x0_k<<<MM, 256, 0, stream>>>(C, 4100, 4099, mc);
    // 9. out[...,1:] = lx2[...,1:] + h @ w_mlp_shrink + b
    sgemm_k<true, false, true><<<dim3(16, 64), 256, 0, stream>>>(
        C, 4100, w_ms, 1024, b_ms, X2, 1024, out + 1, 1025, 1024, 4100);
    // 10. out[...,0]
    row_x0_k<<<MM, 256, 0, stream>>>(out, 1025, 1024, bc);
}

// Round 4
// 1251.987 us; speedup vs baseline: 4.8778x; 2.3938x over previous
//
#include <hip/hip_runtime.h>
#include <math.h>

// Problem constants: B=2, T=2048, E=1024, H=16, D=64; M = B*T = 4096
#define MM   4096
#define TT   2048
#define HH   16

typedef __bf16 bf16x8 __attribute__((ext_vector_type(8)));
typedef float f32x4 __attribute__((ext_vector_type(4)));

// async global->LDS, 16B per lane; LDS dest = wave-uniform base + lane*16
__device__ __forceinline__ void g2l16(const void* g, void* l) {
    __builtin_amdgcn_global_load_lds(
        (__attribute__((address_space(1))) void*)g,
        (__attribute__((address_space(3))) void*)l, 16, 0, 0);
}

// ---------------------------------------------------------------- reductions
__device__ __forceinline__ float blockSum256(float v, volatile float* sb) {
    int lane = threadIdx.x & 63, w = threadIdx.x >> 6;
#pragma unroll
    for (int o = 32; o; o >>= 1) v += __shfl_xor(v, o);
    if (lane == 0) sb[w] = v;
    __syncthreads();
    v = sb[0] + sb[1] + sb[2] + sb[3];
    __syncthreads();
    return v;
}

// ---------------------------------------------------------------- block_norm -> bf16 (1056-wide, zero pad)
__global__ __launch_bounds__(256) void block_norm_bf_k(
    const float* __restrict__ in, int ld,
    __bf16* __restrict__ out,
    const float* __restrict__ lw, const float* __restrict__ lb,
    const float* __restrict__ curv)
{
    int row = blockIdx.x;
    const float* x = in + (size_t)row * ld;
    __bf16* o = out + (size_t)row * 1056;
    __shared__ float sb[4];
    int tid = threadIdx.x;
    float v[4]; float s1 = 0.f, s2 = 0.f;
#pragma unroll
    for (int r = 0; r < 4; r++) {
        float t = x[tid + 256 * r];
        v[r] = t; s1 += t; s2 += t * t;
    }
    s1 = blockSum256(s1, sb);
    s2 = blockSum256(s2, sb);
    float mean = s1 * (1.f / 1024.f);
    float var  = s2 * (1.f / 1024.f) - mean * mean;
    float rs = rsqrtf(var + 1e-5f);
    float y[4]; float ssq = 0.f;
#pragma unroll
    for (int r = 0; r < 4; r++) {
        int i = tid + 256 * r;
        float t = (v[r] - mean) * rs * lw[i] + lb[i];
        y[r] = t; ssq += t * t;
    }
    ssq = blockSum256(ssq, sb);
#pragma unroll
    for (int r = 0; r < 4; r++) o[1 + tid + 256 * r] = (__bf16)y[r];
    if (tid == 0) o[0] = (__bf16)sqrtf(expf(*curv) + ssq);
    if (tid < 31) o[1025 + tid] = (__bf16)0.f;   // zero pad cols 1025..1055
}

// ---------------------------------------------------------------- row x0 (fp32, final output)
__global__ __launch_bounds__(256) void row_x0_k(
    float* __restrict__ buf, int stride, int n, const float* __restrict__ curv)
{
    int row = blockIdx.x;
    float* base = buf + (size_t)row * stride;
    __shared__ float sb[4];
    float s = 0.f;
    for (int i = threadIdx.x; i < n; i += 256) { float t = base[1 + i]; s += t * t; }
    s = blockSum256(s, sb);
    if (threadIdx.x == 0) base[0] = sqrtf(expf(*curv) + s);
}

// ---------------------------------------------------------------- row x0 (bf16 h buffer, stride 4128, n=4099)
__global__ __launch_bounds__(256) void row_x0_bf_k(
    __bf16* __restrict__ buf, const float* __restrict__ curv)
{
    int row = blockIdx.x;
    __bf16* base = buf + (size_t)row * 4128;
    __shared__ float sb[4];
    float s = 0.f;
    for (int i = threadIdx.x; i < 4099; i += 256) { float t = (float)base[1 + i]; s += t * t; }
    s = blockSum256(s, sb);
    if (threadIdx.x == 0) base[0] = (__bf16)sqrtf(expf(*curv) + s);
    if (threadIdx.x < 28) base[4100 + threadIdx.x] = (__bf16)0.f;  // zero pad 4100..4127
}

// ---------------------------------------------------------------- weight convert + transpose
// W fp32 (K x N) -> Wt bf16 (N x Kp), zero-padded k in [K, Kp)
__global__ __launch_bounds__(256) void wt_k(
    const float* __restrict__ W, int K, int N,
    __bf16* __restrict__ Wt, int Kp)
{
    __shared__ float s[32][33];
    int tx = threadIdx.x & 31, ty = threadIdx.x >> 5;    // 32 x 8
    int k0 = blockIdx.x * 32, n0 = blockIdx.y * 32;
#pragma unroll
    for (int r = 0; r < 4; r++) {
        int k = k0 + ty + 8 * r, n = n0 + tx;
        s[ty + 8 * r][tx] = (k < K && n < N) ? W[(size_t)k * N + n] : 0.f;
    }
    __syncthreads();
#pragma unroll
    for (int r = 0; r < 4; r++) {
        int n = n0 + ty + 8 * r, k = k0 + tx;
        if (n < N) Wt[(size_t)n * Kp + k] = (__bf16)s[tx][ty + 8 * r];
    }
}

// ---------------------------------------------------------------- bf16 MFMA GEMM (m97-style)
// C[m,n] = act( A[m,:] @ Bt[n,:] + bias[n] ) + skip[m,n]
// A: M x Kp bf16 (lda), Bt: N x Kp bf16 (ldb), 128x128 tile, BK=32, 256 thr.
template<bool BIAS, bool GELU, bool SKIP, bool OUTBF>
__global__ __launch_bounds__(256) void mgemm_k(
    const __bf16* __restrict__ A, int lda,
    const __bf16* __restrict__ Bt, int ldb,
    const float* __restrict__ bias,
    const float* __restrict__ skip, int ldskip,
    void* __restrict__ Cout, int ldc,
    int N, int Kp)
{
    __shared__ __bf16 sA[128 * 32];
    __shared__ __bf16 sB[128 * 32];
    int tid = threadIdx.x;
    int w = tid >> 6, lane = tid & 63;
    int m0 = blockIdx.y * 128, n0 = blockIdx.x * 128;
    const __bf16* Ab = A + (size_t)m0 * lda;
    const __bf16* Bb = Bt + (size_t)n0 * ldb;

    f32x4 zero = {0.f, 0.f, 0.f, 0.f};
    f32x4 acc[4][4];
#pragma unroll
    for (int i = 0; i < 4; i++)
#pragma unroll
        for (int j = 0; j < 4; j++) acc[i][j] = zero;

    int mw = (w & 1) * 64, nw = (w >> 1) * 64;
    int lr = lane & 15, lq = lane >> 4;
    int fko = lq * 8;

    // staging: chunk c covers tile row c>>2, k-offset (c&3)*8 (8 bf16 = 16B)
    int c1 = tid, c2 = tid + 256;
    int r1 = c1 >> 2, kk1 = (c1 & 3) * 8;
    int r2 = c2 >> 2, kk2 = (c2 & 3) * 8;
    __bf16* lA1 = &sA[(size_t)(w * 64) * 8];
    __bf16* lA2 = &sA[(size_t)(256 + w * 64) * 8];
    __bf16* lB1 = &sB[(size_t)(w * 64) * 8];
    __bf16* lB2 = &sB[(size_t)(256 + w * 64) * 8];

    for (int k0 = 0; k0 < Kp; k0 += 32) {
        g2l16(Ab + (size_t)r1 * lda + k0 + kk1, lA1);
        g2l16(Ab + (size_t)r2 * lda + k0 + kk2, lA2);
        g2l16(Bb + (size_t)r1 * ldb + k0 + kk1, lB1);
        g2l16(Bb + (size_t)r2 * ldb + k0 + kk2, lB2);
        __syncthreads();   // drains vmcnt (global_load_lds) + barrier
        bf16x8 af[4], bf[4];
#pragma unroll
        for (int i = 0; i < 4; i++) af[i] = *(const bf16x8*)&sA[(mw + i * 16 + lr) * 32 + fko];
#pragma unroll
        for (int j = 0; j < 4; j++) bf[j] = *(const bf16x8*)&sB[(nw + j * 16 + lr) * 32 + fko];
#pragma unroll
        for (int i = 0; i < 4; i++)
#pragma unroll
            for (int j = 0; j < 4; j++)
                acc[i][j] = __builtin_amdgcn_mfma_f32_16x16x32_bf16(af[i], bf[j], acc[i][j], 0, 0, 0);
        __syncthreads();
    }

    // epilogue: D layout col = lane&15, row = (lane>>4)*4 + reg
#pragma unroll
    for (int j = 0; j < 4; j++) {
        int n = n0 + nw + j * 16 + lr;
        if (n < N) {
            float bv = BIAS ? bias[n] : 0.f;
#pragma unroll
            for (int i = 0; i < 4; i++) {
#pragma unroll
                for (int r = 0; r < 4; r++) {
                    int m = m0 + mw + i * 16 + lq * 4 + r;
                    float v = acc[i][j][r] + bv;
                    if (GELU) v = 0.5f * v * (1.f + erff(v * 0.70710678118654752f));
                    if (SKIP) v += skip[(size_t)m * ldskip + n];
                    if (OUTBF) ((__bf16*)Cout)[(size_t)m * ldc + n] = (__bf16)v;
                    else       ((float*)Cout)[(size_t)m * ldc + n] = v;
                }
            }
        }
    }
}

// ---------------------------------------------------------------- RoPE in-place + norms + o_bf pad zero
__global__ __launch_bounds__(256) void rope_k(
    float* __restrict__ QKV, const float* __restrict__ curv,
    float* __restrict__ qt, float* __restrict__ kt, float* __restrict__ vt,
    __bf16* __restrict__ Obf)
{
    int row = blockIdx.x;              // b*T + t
    int b = row >> 11, t = row & (TT - 1);
    int wv = threadIdx.x >> 6, d = threadIdx.x & 63;
    int j = d & 31;
    float fr = (float)t * powf(10000.0f, -(float)(2 * j) / 64.0f);
    float cv = cosf(fr), sv = sinf(fr);
    float sgn = (d < 32) ? sv : -sv;
    for (int h = wv; h < HH; h += 4) {
        float Kh = expf(curv[h]);
        float* base = QKV + (size_t)row * 3072 + h * 64;
        float q = base[d], k = base[1024 + d], v = base[2048 + d];
        float qp = __shfl_xor(q, 32);
        float kp = __shfl_xor(k, 32);
        float qr = q * cv + qp * sgn;
        float kr = k * cv + kp * sgn;
        base[d] = qr; base[1024 + d] = kr;   // in-place (regs read before write)
        float sq = qr * qr, sk = kr * kr, sv2 = v * v;
#pragma unroll
        for (int o = 32; o; o >>= 1) {
            sq  += __shfl_xor(sq, o);
            sk  += __shfl_xor(sk, o);
            sv2 += __shfl_xor(sv2, o);
        }
        size_t oidx = ((size_t)(b * HH + h) * TT + t);
        if (d == 0) {
            qt[oidx] = sqrtf(Kh + sq);
            kt[oidx] = sqrtf(Kh + sk);
            vt[oidx] = sqrtf(Kh + sv2);
        }
    }
    if (threadIdx.x < 16) Obf[(size_t)row * 1056 + 1040 + threadIdx.x] = (__bf16)0.f;
}

// ---------------------------------------------------------------- flash hyperbolic attention (v3)
// 1 query per 4-lane group (TQ=64). Reads q/k/v head-strided from qkv buffer.
// Writes bf16 o_t (M x 1056), col h*65 + e.
#define FT_TQ 64
#define FT_TS 64
__global__ __launch_bounds__(256, 4) void flash_k(
    const float* __restrict__ QKV,
    const float* __restrict__ qt, const float* __restrict__ kt,
    const float* __restrict__ vt,
    const float* __restrict__ curv,
    __bf16* __restrict__ O)
{
    __shared__ float sK[FT_TS * 64];
    __shared__ float sV[FT_TS * 64];
    __shared__ float skt[FT_TS];
    __shared__ float svt[FT_TS];

    int bh = blockIdx.y; int h = bh & (HH - 1); int b = bh >> 4;
    int qbase = ((int)gridDim.x - 1 - (int)blockIdx.x) * FT_TQ;  // longest first
    float Kh = expf(curv[h]); float sqKh = sqrtf(Kh);
    float negInvKh = -1.0f / Kh;
    const float* tok = QKV + (size_t)b * TT * 3072 + h * 64;  // +t*3072 (+1024 k, +2048 v)
    const float* qtp = qt + (size_t)bh * TT;
    const float* ktp = kt + (size_t)bh * TT;
    const float* vtp = vt + (size_t)bh * TT;

    int tid = threadIdx.x;
    int g = tid & 3, qp = tid >> 2;
    int q0 = qbase + qp;
    bool g1 = (g & 1), g2b = (g & 2);

    float qreg[16];
    {
        const float* qrow = tok + (size_t)q0 * 3072 + g * 16;
#pragma unroll
        for (int j2 = 0; j2 < 16; j2 += 4) {
            float4 f = *(const float4*)(qrow + j2);
            qreg[j2] = f.x; qreg[j2 + 1] = f.y; qreg[j2 + 2] = f.z; qreg[j2 + 3] = f.w;
        }
    }
    float qtv = qtp[q0];
    float acc[16] = {};
    float acc0 = 0.f, lsum = 0.f;

    int send = qbase + FT_TQ;
    for (int sb = 0; sb < send; sb += FT_TS) {
        __syncthreads();
#pragma unroll
        for (int r = 0; r < 4; r++) {
            int idx = tid + 256 * r;            // float4 chunk, 0..1023
            int row = idx >> 4, col = (idx & 15) * 4;
            const float* src = tok + (size_t)(sb + row) * 3072 + col;
            *(float4*)&sK[row * 64 + col] = *(const float4*)(src + 1024);
            *(float4*)&sV[row * 64 + col] = *(const float4*)(src + 2048);
        }
        if (tid < FT_TS) skt[tid] = ktp[sb + tid];
        else if (tid < 2 * FT_TS) svt[tid - FT_TS] = vtp[sb + tid - FT_TS];
        __syncthreads();

        for (int s0 = 0; s0 < FT_TS; s0 += 4) {
            float part[4] = {};
#pragma unroll
            for (int jj = 0; jj < 4; jj++) {
                const float* kcol = &sK[(s0 + jj) * 64 + g * 16];
#pragma unroll
                for (int d = 0; d < 16; d += 4) {
                    float4 kv = *(const float4*)(kcol + d);
                    part[jj] += qreg[d] * kv.x + qreg[d + 1] * kv.y
                              + qreg[d + 2] * kv.z + qreg[d + 3] * kv.w;
                }
            }
            // transpose-reduce: lane g ends with full dot for s-col g
            float y0 = g1 ? part[1] : part[0];
            float z0 = g1 ? part[0] : part[1];
            float y1 = g1 ? part[3] : part[2];
            float z1 = g1 ? part[2] : part[3];
            float r0 = y0 + __shfl_xor(z0, 1);
            float r1 = y1 + __shfl_xor(z1, 1);
            float u = g2b ? r1 : r0;
            float wv2 = g2b ? r0 : r1;
            float own = u + __shfl_xor(wv2, 2);
            // logit -> p
            int scol = sb + s0 + g;
            float ktv = skt[s0 + g];
            float inner = own - qtv * ktv;
            float ratio = fmaxf(inner * negInvKh, 1.0f + 1e-7f);
            float yy = ratio + sqrtf(ratio * ratio - 1.0f);
            float pv = exp2f(-sqKh * log2f(yy));
            float pown = (scol <= q0) ? pv : 0.f;
            // share p across 4-lane group
            float pa[4];
            pa[0] = pown;
            pa[1] = __shfl_xor(pown, 1);
            pa[2] = __shfl_xor(pown, 2);
            pa[3] = __shfl_xor(pa[1], 2);
            lsum += (pa[0] + pa[1]) + (pa[2] + pa[3]);
            // PV accumulate
#pragma unroll
            for (int m = 0; m < 4; m++) {
                int srow = s0 + (g ^ m);
                const float* vrow = &sV[srow * 64 + g * 16];
                acc0 += pa[m] * svt[srow];
#pragma unroll
                for (int d = 0; d < 16; d += 4) {
                    float4 vv = *(const float4*)(vrow + d);
                    acc[d]     += pa[m] * vv.x;
                    acc[d + 1] += pa[m] * vv.y;
                    acc[d + 2] += pa[m] * vv.z;
                    acc[d + 3] += pa[m] * vv.w;
                }
            }
        }
    }

    // epilogue: normalize, Lorentz-scale, write bf16 token-major (M,1056)
    float inv = 1.0f / lsum;
    float o0 = acc0 * inv;
    float prt = 0.f;
#pragma unroll
    for (int j2 = 0; j2 < 16; j2++) { float t = acc[j2] * inv; acc[j2] = t; prt += t * t; }
    prt += __shfl_xor(prt, 1);
    prt += __shfl_xor(prt, 2);
    float ln2v = o0 * o0 - prt;
    float scale = sqKh * rsqrtf(fmaxf(ln2v, 1e-12f));
    size_t orow = (size_t)(b * TT + q0) * 1056 + h * 65;
    if (g == 0) O[orow] = (__bf16)(o0 * scale);
#pragma unroll
    for (int j2 = 0; j2 < 16; j2++) O[orow + 1 + g * 16 + j2] = (__bf16)(acc[j2] * scale);
}

// ---------------------------------------------------------------- launch
extern "C" void kernel_launch(void* const* d_in, const int* in_sizes, int n_in,
                              void* d_out, int out_size, void* d_ws, size_t ws_size,
                              hipStream_t stream) {
    const float* x    = (const float*)d_in[0];
    const float* bc   = (const float*)d_in[1];
    const float* mc   = (const float*)d_in[2];
    const float* ac   = (const float*)d_in[3];
    const float* w_qkv = (const float*)d_in[4];
    const float* w_ap  = (const float*)d_in[5];
    const float* b_ap  = (const float*)d_in[6];
    const float* w_me  = (const float*)d_in[7];
    const float* b_me  = (const float*)d_in[8];
    const float* w_ms  = (const float*)d_in[9];
    const float* b_ms  = (const float*)d_in[10];
    const float* lnw  = (const float*)d_in[11];
    const float* lnb  = (const float*)d_in[12];
    float* out = (float*)d_out;
    float* ws  = (float*)d_ws;

    // ---- workspace layout (floats), total 23,610,928 fl = 94.4 MB ----
    // R (12,648,448 fl): qkv fp32 (M*3072, steps 2-4), then X2 fp32 [0..4.19M)
    //   from step 5, h_bf bf16 (M*4128) at R+4,194,304 fl from step 7.
    float* R      = ws;
    float* qkvbuf = R;
    float* X2     = R;
    __bf16* h_bf  = (__bf16*)(R + 4194304);
    float* p      = R + 12648448;
    __bf16* ln_bf = (__bf16*)p;  p += 2162688;   // M*1056
    __bf16* o_bf  = (__bf16*)p;  p += 2162688;   // M*1056
    __bf16* qkvT  = (__bf16*)p;  p += 1622016;   // 3072*1056
    __bf16* apT   = (__bf16*)p;  p += 540672;    // 1024*1056
    __bf16* meT   = (__bf16*)p;  p += 2164272;   // 4099*1056
    __bf16* msT   = (__bf16*)p;  p += 2113536;   // 1024*4128
    float* Qt = p;               p += 2 * HH * TT;
    float* Kt = p;               p += 2 * HH * TT;
    float* Vt = p;

    // 0. weight convert + transpose (fp32 KxN -> bf16 NxKp)
    wt_k<<<dim3(33, 96),  256, 0, stream>>>(w_qkv, 1025, 3072, qkvT, 1056);
    wt_k<<<dim3(33, 32),  256, 0, stream>>>(w_ap,  1040, 1024, apT,  1056);
    wt_k<<<dim3(33, 129), 256, 0, stream>>>(w_me,  1025, 4099, meT,  1056);
    wt_k<<<dim3(129, 32), 256, 0, stream>>>(w_ms,  4100, 1024, msT,  4128);

    // 1. ln1 = block_norm(project(x)) -> bf16 (lx1[...,1:] == x)
    block_norm_bf_k<<<MM, 256, 0, stream>>>(x, 1024, ln_bf, lnw, lnb, bc);
    // 2. qkv = ln1 @ w_qkv -> fp32 (M,3072)
    mgemm_k<false, false, false, false><<<dim3(24, 32), 256, 0, stream>>>(
        ln_bf, 1056, qkvT, 1056, nullptr, nullptr, 0, qkvbuf, 3072, 3072, 1056);
    // 3. RoPE in-place + row norms + o_bf pad zero
    rope_k<<<MM, 256, 0, stream>>>(qkvbuf, ac, Qt, Kt, Vt, o_bf);
    // 4. attention -> o_t bf16 (M,1056)
    flash_k<<<dim3(TT / FT_TQ, 2 * HH), 256, 0, stream>>>(qkvbuf, Qt, Kt, Vt, ac, o_bf);
    // 5. lx2[...,1:] = x + o_t @ w_attn_proj + b -> X2 fp32 (overwrites qkv head; qkv dead)
    mgemm_k<true, false, true, false><<<dim3(8, 32), 256, 0, stream>>>(
        o_bf, 1056, apT, 1056, b_ap, x, 1024, X2, 1024, 1024, 1056);
    // 6. ln2 = block_norm(lx2) -> bf16
    block_norm_bf_k<<<MM, 256, 0, stream>>>(X2, 1024, ln_bf, lnw, lnb, bc);
    // 7. h = gelu(ln2 @ w_mlp_expand + b) -> bf16 cols 1..4099 of h_bf
    mgemm_k<true, true, false, true><<<dim3(33, 32), 256, 0, stream>>>(
        ln_bf, 1056, meT, 1056, b_me, nullptr, 0, (void*)(h_bf + 1), 4128, 4099, 1056);
    // 8. h x0 column + pad zero (bf16)
    row_x0_bf_k<<<MM, 256, 0, stream>>>(h_bf, mc);
    // 9. out[...,1:] = lx2[...,1:] + h @ w_mlp_shrink + b (Kp=4128)
    mgemm_k<true, false, true, false><<<dim3(8, 32), 256, 0, stream>>>(
        h_bf, 4128, msT, 4128, b_ms, X2, 1024, out + 1, 1025, 1024, 4128);
    // 10. out[...,0]
    row_x0_k<<<MM, 256, 0, stream>>>(out, 1025, 1024, bc);
}

// Round 5
// 648.287 us; speedup vs baseline: 9.4202x; 1.9312x over previous
//
#include <hip/hip_runtime.h>
#include <math.h>

// Problem constants: B=2, T=2048, E=1024, H=16, D=64; M = B*T = 4096
#define MM   4096
#define TT   2048
#define HH   16

typedef __bf16 bf16x8 __attribute__((ext_vector_type(8)));
typedef __bf16 bf16x4 __attribute__((ext_vector_type(4)));
typedef float f32x4 __attribute__((ext_vector_type(4)));

// async global->LDS, 16B per lane; LDS dest = wave-uniform base + lane*16
__device__ __forceinline__ void g2l16(const void* g, void* l) {
    __builtin_amdgcn_global_load_lds(
        (__attribute__((address_space(1))) void*)g,
        (__attribute__((address_space(3))) void*)l, 16, 0, 0);
}

__device__ __forceinline__ bf16x8 cvt8(float4 a, float4 b) {
    bf16x8 r;
    r[0] = (__bf16)a.x; r[1] = (__bf16)a.y; r[2] = (__bf16)a.z; r[3] = (__bf16)a.w;
    r[4] = (__bf16)b.x; r[5] = (__bf16)b.y; r[6] = (__bf16)b.z; r[7] = (__bf16)b.w;
    return r;
}

// ---------------------------------------------------------------- reductions
__device__ __forceinline__ float blockSum256(float v, volatile float* sb) {
    int lane = threadIdx.x & 63, w = threadIdx.x >> 6;
#pragma unroll
    for (int o = 32; o; o >>= 1) v += __shfl_xor(v, o);
    if (lane == 0) sb[w] = v;
    __syncthreads();
    v = sb[0] + sb[1] + sb[2] + sb[3];
    __syncthreads();
    return v;
}

// ---------------------------------------------------------------- block_norm -> bf16 (1056-wide, zero pad)
__global__ __launch_bounds__(256) void block_norm_bf_k(
    const float* __restrict__ in, int ld,
    __bf16* __restrict__ out,
    const float* __restrict__ lw, const float* __restrict__ lb,
    const float* __restrict__ curv)
{
    int row = blockIdx.x;
    const float* x = in + (size_t)row * ld;
    __bf16* o = out + (size_t)row * 1056;
    __shared__ float sb[4];
    int tid = threadIdx.x;
    float v[4]; float s1 = 0.f, s2 = 0.f;
#pragma unroll
    for (int r = 0; r < 4; r++) {
        float t = x[tid + 256 * r];
        v[r] = t; s1 += t; s2 += t * t;
    }
    s1 = blockSum256(s1, sb);
    s2 = blockSum256(s2, sb);
    float mean = s1 * (1.f / 1024.f);
    float var  = s2 * (1.f / 1024.f) - mean * mean;
    float rs = rsqrtf(var + 1e-5f);
    float y[4]; float ssq = 0.f;
#pragma unroll
    for (int r = 0; r < 4; r++) {
        int i = tid + 256 * r;
        float t = (v[r] - mean) * rs * lw[i] + lb[i];
        y[r] = t; ssq += t * t;
    }
    ssq = blockSum256(ssq, sb);
#pragma unroll
    for (int r = 0; r < 4; r++) o[1 + tid + 256 * r] = (__bf16)y[r];
    if (tid == 0) o[0] = (__bf16)sqrtf(expf(*curv) + ssq);
    if (tid < 31) o[1025 + tid] = (__bf16)0.f;   // zero pad cols 1025..1055
}

// ---------------------------------------------------------------- row x0 (fp32, final output)
__global__ __launch_bounds__(256) void row_x0_k(
    float* __restrict__ buf, int stride, int n, const float* __restrict__ curv)
{
    int row = blockIdx.x;
    float* base = buf + (size_t)row * stride;
    __shared__ float sb[4];
    float s = 0.f;
    for (int i = threadIdx.x; i < n; i += 256) { float t = base[1 + i]; s += t * t; }
    s = blockSum256(s, sb);
    if (threadIdx.x == 0) base[0] = sqrtf(expf(*curv) + s);
}

// ---------------------------------------------------------------- row x0 (bf16 h buffer, stride 4128, n=4099)
__global__ __launch_bounds__(256) void row_x0_bf_k(
    __bf16* __restrict__ buf, const float* __restrict__ curv)
{
    int row = blockIdx.x;
    __bf16* base = buf + (size_t)row * 4128;
    __shared__ float sb[4];
    float s = 0.f;
    for (int i = threadIdx.x; i < 4099; i += 256) { float t = (float)base[1 + i]; s += t * t; }
    s = blockSum256(s, sb);
    if (threadIdx.x == 0) base[0] = (__bf16)sqrtf(expf(*curv) + s);
    if (threadIdx.x < 28) base[4100 + threadIdx.x] = (__bf16)0.f;  // zero pad 4100..4127
}

// ---------------------------------------------------------------- weight convert + transpose
// W fp32 (K x N) -> Wt bf16 (N x Kp), zero-padded k in [K, Kp)
__global__ __launch_bounds__(256) void wt_k(
    const float* __restrict__ W, int K, int N,
    __bf16* __restrict__ Wt, int Kp)
{
    __shared__ float s[32][33];
    int tx = threadIdx.x & 31, ty = threadIdx.x >> 5;    // 32 x 8
    int k0 = blockIdx.x * 32, n0 = blockIdx.y * 32;
#pragma unroll
    for (int r = 0; r < 4; r++) {
        int k = k0 + ty + 8 * r, n = n0 + tx;
        s[ty + 8 * r][tx] = (k < K && n < N) ? W[(size_t)k * N + n] : 0.f;
    }
    __syncthreads();
#pragma unroll
    for (int r = 0; r < 4; r++) {
        int n = n0 + ty + 8 * r, k = k0 + tx;
        if (n < N) Wt[(size_t)n * Kp + k] = (__bf16)s[tx][ty + 8 * r];
    }
}

// ---------------------------------------------------------------- bf16 MFMA GEMM (m97-style)
template<bool BIAS, bool GELU, bool SKIP, bool OUTBF>
__global__ __launch_bounds__(256) void mgemm_k(
    const __bf16* __restrict__ A, int lda,
    const __bf16* __restrict__ Bt, int ldb,
    const float* __restrict__ bias,
    const float* __restrict__ skip, int ldskip,
    void* __restrict__ Cout, int ldc,
    int N, int Kp)
{
    __shared__ __bf16 sA[128 * 32];
    __shared__ __bf16 sB[128 * 32];
    int tid = threadIdx.x;
    int w = tid >> 6, lane = tid & 63;
    int m0 = blockIdx.y * 128, n0 = blockIdx.x * 128;
    const __bf16* Ab = A + (size_t)m0 * lda;
    const __bf16* Bb = Bt + (size_t)n0 * ldb;

    f32x4 zero = {0.f, 0.f, 0.f, 0.f};
    f32x4 acc[4][4];
#pragma unroll
    for (int i = 0; i < 4; i++)
#pragma unroll
        for (int j = 0; j < 4; j++) acc[i][j] = zero;

    int mw = (w & 1) * 64, nw = (w >> 1) * 64;
    int lr = lane & 15, lq = lane >> 4;
    int fko = lq * 8;

    int c1 = tid, c2 = tid + 256;
    int r1 = c1 >> 2, kk1 = (c1 & 3) * 8;
    int r2 = c2 >> 2, kk2 = (c2 & 3) * 8;
    __bf16* lA1 = &sA[(size_t)(w * 64) * 8];
    __bf16* lA2 = &sA[(size_t)(256 + w * 64) * 8];
    __bf16* lB1 = &sB[(size_t)(w * 64) * 8];
    __bf16* lB2 = &sB[(size_t)(256 + w * 64) * 8];

    for (int k0 = 0; k0 < Kp; k0 += 32) {
        g2l16(Ab + (size_t)r1 * lda + k0 + kk1, lA1);
        g2l16(Ab + (size_t)r2 * lda + k0 + kk2, lA2);
        g2l16(Bb + (size_t)r1 * ldb + k0 + kk1, lB1);
        g2l16(Bb + (size_t)r2 * ldb + k0 + kk2, lB2);
        __syncthreads();
        bf16x8 af[4], bf[4];
#pragma unroll
        for (int i = 0; i < 4; i++) af[i] = *(const bf16x8*)&sA[(mw + i * 16 + lr) * 32 + fko];
#pragma unroll
        for (int j = 0; j < 4; j++) bf[j] = *(const bf16x8*)&sB[(nw + j * 16 + lr) * 32 + fko];
#pragma unroll
        for (int i = 0; i < 4; i++)
#pragma unroll
            for (int j = 0; j < 4; j++)
                acc[i][j] = __builtin_amdgcn_mfma_f32_16x16x32_bf16(af[i], bf[j], acc[i][j], 0, 0, 0);
        __syncthreads();
    }

#pragma unroll
    for (int j = 0; j < 4; j++) {
        int n = n0 + nw + j * 16 + lr;
        if (n < N) {
            float bv = BIAS ? bias[n] : 0.f;
#pragma unroll
            for (int i = 0; i < 4; i++) {
#pragma unroll
                for (int r = 0; r < 4; r++) {
                    int m = m0 + mw + i * 16 + lq * 4 + r;
                    float v = acc[i][j][r] + bv;
                    if (GELU) v = 0.5f * v * (1.f + erff(v * 0.70710678118654752f));
                    if (SKIP) v += skip[(size_t)m * ldskip + n];
                    if (OUTBF) ((__bf16*)Cout)[(size_t)m * ldc + n] = (__bf16)v;
                    else       ((float*)Cout)[(size_t)m * ldc + n] = v;
                }
            }
        }
    }
}

// ---------------------------------------------------------------- RoPE in-place + norms + o_bf pad zero
__global__ __launch_bounds__(256) void rope_k(
    float* __restrict__ QKV, const float* __restrict__ curv,
    float* __restrict__ qt, float* __restrict__ kt, float* __restrict__ vt,
    __bf16* __restrict__ Obf)
{
    int row = blockIdx.x;              // b*T + t
    int b = row >> 11, t = row & (TT - 1);
    int wv = threadIdx.x >> 6, d = threadIdx.x & 63;
    int j = d & 31;
    float fr = (float)t * powf(10000.0f, -(float)(2 * j) / 64.0f);
    float cv = cosf(fr), sv = sinf(fr);
    float sgn = (d < 32) ? sv : -sv;
    for (int h = wv; h < HH; h += 4) {
        float Kh = expf(curv[h]);
        float* base = QKV + (size_t)row * 3072 + h * 64;
        float q = base[d], k = base[1024 + d], v = base[2048 + d];
        float qp = __shfl_xor(q, 32);
        float kp = __shfl_xor(k, 32);
        float qr = q * cv + qp * sgn;
        float kr = k * cv + kp * sgn;
        base[d] = qr; base[1024 + d] = kr;   // in-place (regs read before write)
        float sq = qr * qr, sk = kr * kr, sv2 = v * v;
#pragma unroll
        for (int o = 32; o; o >>= 1) {
            sq  += __shfl_xor(sq, o);
            sk  += __shfl_xor(sk, o);
            sv2 += __shfl_xor(sv2, o);
        }
        size_t oidx = ((size_t)(b * HH + h) * TT + t);
        if (d == 0) {
            qt[oidx] = sqrtf(Kh + sq);
            kt[oidx] = sqrtf(Kh + sk);
            vt[oidx] = sqrtf(Kh + sv2);
        }
    }
    if (threadIdx.x < 16) Obf[(size_t)row * 1056 + 1040 + threadIdx.x] = (__bf16)0.f;
}

// ---------------------------------------------------------------- MFMA flash hyperbolic attention (v4)
// Block = 4 waves = paired q-tiles (pi, 63-pi) of 32 queries (balanced causal
// work). Each wave owns one 16-query m-tile: QK^T via bf16 MFMA with q hi+lo
// split (2 products; qt*kt cancellation stays fp32 in epilogue); P -> LDS
// (bf16, per-wave private) -> PV via MFMA. lsum & o0 (vt col) accumulate in
// the score epilogue. All LDS tiles stride-72 bf16 rows -> b128 frags 2-way.
__global__ __launch_bounds__(256, 4) void flash_k(
    const float* __restrict__ QKV,
    const float* __restrict__ qt, const float* __restrict__ kt,
    const float* __restrict__ vt,
    const float* __restrict__ curv,
    __bf16* __restrict__ O)
{
    __shared__ __bf16 sK[64 * 72];
    __shared__ __bf16 sVt[64 * 72];
    __shared__ __bf16 sP[4 * 16 * 72];
    __shared__ float skt[64], svt[64];

    int bh = blockIdx.y; int h = bh & (HH - 1); int b = bh >> 4;
    int pi = blockIdx.x;                   // pair index 0..31
    float Kh = expf(curv[h]);
    float sqKh = sqrtf(Kh), msqK = -sqKh, invKh = 1.0f / Kh;
    const float* tok = QKV + (size_t)b * TT * 3072 + h * 64;  // q; +1024 k; +2048 v
    const float* qtp = qt + (size_t)bh * TT;
    const float* ktp = kt + (size_t)bh * TT;
    const float* vtp = vt + (size_t)bh * TT;

    int tid = threadIdx.x;
    int w = tid >> 6, lane = tid & 63;
    int m = lane & 15, quad = lane >> 4;
    int qA = pi * 32, qB = (63 - pi) * 32;
    int myBase = (w < 2) ? (qA + 16 * w) : (qB + 16 * (w - 2));
    int myJmax = (myBase + 15) >> 6;
    int blockJmax = (qB + 31) >> 6;
    __bf16* sPw = &sP[w * 16 * 72];

    // Q fragments (hi + lo bf16), A-layout: A[m=lane&15][k=quad*8+j+32*ks]
    bf16x8 qhi[2], qlo[2];
    {
        const float* qrow = tok + (size_t)(myBase + m) * 3072;
#pragma unroll
        for (int ks = 0; ks < 2; ks++) {
            const float* s = qrow + quad * 8 + 32 * ks;
            float4 f0 = *(const float4*)s;
            float4 f1 = *(const float4*)(s + 4);
            float fa[8] = {f0.x, f0.y, f0.z, f0.w, f1.x, f1.y, f1.z, f1.w};
#pragma unroll
            for (int jj = 0; jj < 8; jj++) {
                __bf16 hv = (__bf16)fa[jj];
                qhi[ks][jj] = hv;
                qlo[ks][jj] = (__bf16)(fa[jj] - (float)hv);
            }
        }
    }
    float qtv[4]; int qg[4];
#pragma unroll
    for (int r = 0; r < 4; r++) { qg[r] = myBase + quad * 4 + r; qtv[r] = qtp[qg[r]]; }

    f32x4 zero = {0.f, 0.f, 0.f, 0.f};
    f32x4 accO[4];
#pragma unroll
    for (int nt = 0; nt < 4; nt++) accO[nt] = zero;
    float lsumr[4] = {}, o0r[4] = {};

    // staging coords
    int ks_ = tid >> 2, kd_ = (tid & 3) * 16;        // K: row s, 16 d
    int vs_ = (tid & 15) * 4, vd_ = (tid >> 4) * 4;  // V: 4x4 block transpose

    for (int j = 0; j <= blockJmax; ++j) {
        int sb = j << 6;
        __syncthreads();
        // ---- stage K (bf16, [s][d] stride 72) ----
        {
            const float* kr = tok + (size_t)(sb + ks_) * 3072 + 1024 + kd_;
            float4 k0 = *(const float4*)kr;
            float4 k1 = *(const float4*)(kr + 4);
            float4 k2 = *(const float4*)(kr + 8);
            float4 k3 = *(const float4*)(kr + 12);
            *(bf16x8*)&sK[ks_ * 72 + kd_]     = cvt8(k0, k1);
            *(bf16x8*)&sK[ks_ * 72 + kd_ + 8] = cvt8(k2, k3);
        }
        // ---- stage V transposed (bf16, [d][s] stride 72) ----
        {
            const float* vr = tok + (size_t)(sb + vs_) * 3072 + 2048 + vd_;
            float4 r0 = *(const float4*)vr;
            float4 r1 = *(const float4*)(vr + 3072);
            float4 r2 = *(const float4*)(vr + 6144);
            float4 r3 = *(const float4*)(vr + 9216);
            bf16x4 c0 = {(__bf16)r0.x, (__bf16)r1.x, (__bf16)r2.x, (__bf16)r3.x};
            bf16x4 c1 = {(__bf16)r0.y, (__bf16)r1.y, (__bf16)r2.y, (__bf16)r3.y};
            bf16x4 c2 = {(__bf16)r0.z, (__bf16)r1.z, (__bf16)r2.z, (__bf16)r3.z};
            bf16x4 c3 = {(__bf16)r0.w, (__bf16)r1.w, (__bf16)r2.w, (__bf16)r3.w};
            *(bf16x4*)&sVt[(vd_ + 0) * 72 + vs_] = c0;
            *(bf16x4*)&sVt[(vd_ + 1) * 72 + vs_] = c1;
            *(bf16x4*)&sVt[(vd_ + 2) * 72 + vs_] = c2;
            *(bf16x4*)&sVt[(vd_ + 3) * 72 + vs_] = c3;
        }
        if (tid < 64) skt[tid] = ktp[sb + tid];
        else if (tid < 128) svt[tid - 64] = vtp[sb + tid - 64];
        __syncthreads();

        if (j > myJmax) continue;

        // ---- QK^T: S[16 x 64] ----
        f32x4 accS[4];
#pragma unroll
        for (int nt = 0; nt < 4; nt++) accS[nt] = zero;
#pragma unroll
        for (int nt = 0; nt < 4; nt++) {
#pragma unroll
            for (int ksp = 0; ksp < 2; ksp++) {
                bf16x8 bk = *(const bf16x8*)&sK[(nt * 16 + m) * 72 + ksp * 32 + quad * 8];
                accS[nt] = __builtin_amdgcn_mfma_f32_16x16x32_bf16(qhi[ksp], bk, accS[nt], 0, 0, 0);
                accS[nt] = __builtin_amdgcn_mfma_f32_16x16x32_bf16(qlo[ksp], bk, accS[nt], 0, 0, 0);
            }
        }
        // ---- score epilogue: hyperbolic logit -> p (bf16), lsum/o0 accum ----
#pragma unroll
        for (int nt = 0; nt < 4; nt++) {
            int col = nt * 16 + m;
            int sglob = sb + col;
            float ktv = skt[col], vtv = svt[col];
#pragma unroll
            for (int r = 0; r < 4; r++) {
                float dot = accS[nt][r];
                float rdiff = fmaf(qtv[r], ktv, -dot);          // qt*kt - q.k
                float ratio = fmaxf(rdiff * invKh, 1.0f + 1e-7f);
                float y = ratio + sqrtf(fmaf(ratio, ratio, -1.0f));
                float pv = exp2f(msqK * log2f(y));              // exp(-sqrt(K)*acosh)
                float p = (sglob <= qg[r]) ? pv : 0.0f;
                __bf16 pb = (__bf16)p;
                float pf = (float)pb;                           // rounded, consistent with PV
                lsumr[r] += pf;
                o0r[r] += pf * vtv;
                sPw[(quad * 4 + r) * 72 + col] = pb;
            }
        }
        __asm__ volatile("s_waitcnt lgkmcnt(0)" ::: "memory");
        // ---- PV: O += P @ V ----
#pragma unroll
        for (int ksp = 0; ksp < 2; ksp++) {
            bf16x8 aP = *(const bf16x8*)&sPw[m * 72 + ksp * 32 + quad * 8];
#pragma unroll
            for (int nt = 0; nt < 4; nt++) {
                bf16x8 bV = *(const bf16x8*)&sVt[(nt * 16 + m) * 72 + ksp * 32 + quad * 8];
                accO[nt] = __builtin_amdgcn_mfma_f32_16x16x32_bf16(aP, bV, accO[nt], 0, 0, 0);
            }
        }
    }

    // ---- final: reduce lsum/o0 over the 16 cols-lanes, normalize, write ----
#pragma unroll
    for (int r = 0; r < 4; r++) {
#pragma unroll
        for (int off = 1; off < 16; off <<= 1) {
            lsumr[r] += __shfl_xor(lsumr[r], off);
            o0r[r]   += __shfl_xor(o0r[r], off);
        }
    }
#pragma unroll
    for (int r = 0; r < 4; r++) {
        float inv = 1.0f / lsumr[r];
        float o0f = o0r[r] * inv;
        float ov[4]; float part = 0.f;
#pragma unroll
        for (int nt = 0; nt < 4; nt++) { float t = accO[nt][r] * inv; ov[nt] = t; part += t * t; }
        part += __shfl_xor(part, 1);
        part += __shfl_xor(part, 2);
        part += __shfl_xor(part, 4);
        part += __shfl_xor(part, 8);
        float scale = sqKh * rsqrtf(fmaxf(o0f * o0f - part, 1e-12f));
        size_t orow = (size_t)(b * TT + qg[r]) * 1056 + h * 65;
        if (m == 0) O[orow] = (__bf16)(o0f * scale);
#pragma unroll
        for (int nt = 0; nt < 4; nt++) O[orow + 1 + nt * 16 + m] = (__bf16)(ov[nt] * scale);
    }
}

// ---------------------------------------------------------------- launch
extern "C" void kernel_launch(void* const* d_in, const int* in_sizes, int n_in,
                              void* d_out, int out_size, void* d_ws, size_t ws_size,
                              hipStream_t stream) {
    const float* x    = (const float*)d_in[0];
    const float* bc   = (const float*)d_in[1];
    const float* mc   = (const float*)d_in[2];
    const float* ac   = (const float*)d_in[3];
    const float* w_qkv = (const float*)d_in[4];
    const float* w_ap  = (const float*)d_in[5];
    const float* b_ap  = (const float*)d_in[6];
    const float* w_me  = (const float*)d_in[7];
    const float* b_me  = (const float*)d_in[8];
    const float* w_ms  = (const float*)d_in[9];
    const float* b_ms  = (const float*)d_in[10];
    const float* lnw  = (const float*)d_in[11];
    const float* lnb  = (const float*)d_in[12];
    float* out = (float*)d_out;
    float* ws  = (float*)d_ws;

    float* R      = ws;
    float* qkvbuf = R;
    float* X2     = R;
    __bf16* h_bf  = (__bf16*)(R + 4194304);
    float* p      = R + 12648448;
    __bf16* ln_bf = (__bf16*)p;  p += 2162688;   // M*1056
    __bf16* o_bf  = (__bf16*)p;  p += 2162688;   // M*1056
    __bf16* qkvT  = (__bf16*)p;  p += 1622016;   // 3072*1056
    __bf16* apT   = (__bf16*)p;  p += 540672;    // 1024*1056
    __bf16* meT   = (__bf16*)p;  p += 2164272;   // 4099*1056
    __bf16* msT   = (__bf16*)p;  p += 2113536;   // 1024*4128
    float* Qt = p;               p += 2 * HH * TT;
    float* Kt = p;               p += 2 * HH * TT;
    float* Vt = p;

    // 0. weight convert + transpose
    wt_k<<<dim3(33, 96),  256, 0, stream>>>(w_qkv, 1025, 3072, qkvT, 1056);
    wt_k<<<dim3(33, 32),  256, 0, stream>>>(w_ap,  1040, 1024, apT,  1056);
    wt_k<<<dim3(33, 129), 256, 0, stream>>>(w_me,  1025, 4099, meT,  1056);
    wt_k<<<dim3(129, 32), 256, 0, stream>>>(w_ms,  4100, 1024, msT,  4128);

    // 1. ln1 = block_norm(project(x)) -> bf16
    block_norm_bf_k<<<MM, 256, 0, stream>>>(x, 1024, ln_bf, lnw, lnb, bc);
    // 2. qkv = ln1 @ w_qkv -> fp32 (M,3072)
    mgemm_k<false, false, false, false><<<dim3(24, 32), 256, 0, stream>>>(
        ln_bf, 1056, qkvT, 1056, nullptr, nullptr, 0, qkvbuf, 3072, 3072, 1056);
    // 3. RoPE in-place + row norms + o_bf pad zero
    rope_k<<<MM, 256, 0, stream>>>(qkvbuf, ac, Qt, Kt, Vt, o_bf);
    // 4. MFMA flash attention -> o_t bf16 (M,1056)
    flash_k<<<dim3(32, 2 * HH), 256, 0, stream>>>(qkvbuf, Qt, Kt, Vt, ac, o_bf);
    // 5. lx2[...,1:] = x + o_t @ w_attn_proj + b -> X2 fp32
    mgemm_k<true, false, true, false><<<dim3(8, 32), 256, 0, stream>>>(
        o_bf, 1056, apT, 1056, b_ap, x, 1024, X2, 1024, 1024, 1056);
    // 6. ln2 = block_norm(lx2) -> bf16
    block_norm_bf_k<<<MM, 256, 0, stream>>>(X2, 1024, ln_bf, lnw, lnb, bc);
    // 7. h = gelu(ln2 @ w_mlp_expand + b) -> bf16
    mgemm_k<true, true, false, true><<<dim3(33, 32), 256, 0, stream>>>(
        ln_bf, 1056, meT, 1056, b_me, nullptr, 0, (void*)(h_bf + 1), 4128, 4099, 1056);
    // 8. h x0 column + pad zero
    row_x0_bf_k<<<MM, 256, 0, stream>>>(h_bf, mc);
    // 9. out[...,1:] = lx2[...,1:] + h @ w_mlp_shrink + b
    mgemm_k<true, false, true, false><<<dim3(8, 32), 256, 0, stream>>>(
        h_bf, 4128, msT, 4128, b_ms, X2, 1024, out + 1, 1025, 1024, 4128);
    // 10. out[...,0]
    row_x0_k<<<MM, 256, 0, stream>>>(out, 1025, 1024, bc);
}

// Round 6
// 582.830 us; speedup vs baseline: 10.4782x; 1.1123x over previous
//
#include <hip/hip_runtime.h>
#include <math.h>

// Problem constants: B=2, T=2048, E=1024, H=16, D=64; M = B*T = 4096
#define MM   4096
#define TT   2048
#define HH   16

typedef __bf16 bf16x8 __attribute__((ext_vector_type(8)));
typedef float f32x4 __attribute__((ext_vector_type(4)));

// async global->LDS, 16B per lane; LDS dest = wave-uniform base + lane*16
__device__ __forceinline__ void g2l16(const void* g, void* l) {
    __builtin_amdgcn_global_load_lds(
        (__attribute__((address_space(1))) void*)g,
        (__attribute__((address_space(3))) void*)l, 16, 0, 0);
}

// ---------------------------------------------------------------- reductions
__device__ __forceinline__ float blockSum256(float v, volatile float* sb) {
    int lane = threadIdx.x & 63, w = threadIdx.x >> 6;
#pragma unroll
    for (int o = 32; o; o >>= 1) v += __shfl_xor(v, o);
    if (lane == 0) sb[w] = v;
    __syncthreads();
    v = sb[0] + sb[1] + sb[2] + sb[3];
    __syncthreads();
    return v;
}

// ---------------------------------------------------------------- block_norm -> bf16 (1056-wide, zero pad)
__global__ __launch_bounds__(256) void block_norm_bf_k(
    const float* __restrict__ in, int ld,
    __bf16* __restrict__ out,
    const float* __restrict__ lw, const float* __restrict__ lb,
    const float* __restrict__ curv)
{
    int row = blockIdx.x;
    const float* x = in + (size_t)row * ld;
    __bf16* o = out + (size_t)row * 1056;
    __shared__ float sb[4];
    int tid = threadIdx.x;
    float v[4]; float s1 = 0.f, s2 = 0.f;
#pragma unroll
    for (int r = 0; r < 4; r++) {
        float t = x[tid + 256 * r];
        v[r] = t; s1 += t; s2 += t * t;
    }
    s1 = blockSum256(s1, sb);
    s2 = blockSum256(s2, sb);
    float mean = s1 * (1.f / 1024.f);
    float var  = s2 * (1.f / 1024.f) - mean * mean;
    float rs = rsqrtf(var + 1e-5f);
    float y[4]; float ssq = 0.f;
#pragma unroll
    for (int r = 0; r < 4; r++) {
        int i = tid + 256 * r;
        float t = (v[r] - mean) * rs * lw[i] + lb[i];
        y[r] = t; ssq += t * t;
    }
    ssq = blockSum256(ssq, sb);
#pragma unroll
    for (int r = 0; r < 4; r++) o[1 + tid + 256 * r] = (__bf16)y[r];
    if (tid == 0) o[0] = (__bf16)sqrtf(expf(*curv) + ssq);
    if (tid < 31) o[1025 + tid] = (__bf16)0.f;   // zero pad cols 1025..1055
}

// ---------------------------------------------------------------- row x0 (fp32, final output)
__global__ __launch_bounds__(256) void row_x0_k(
    float* __restrict__ buf, int stride, int n, const float* __restrict__ curv)
{
    int row = blockIdx.x;
    float* base = buf + (size_t)row * stride;
    __shared__ float sb[4];
    float s = 0.f;
    for (int i = threadIdx.x; i < n; i += 256) { float t = base[1 + i]; s += t * t; }
    s = blockSum256(s, sb);
    if (threadIdx.x == 0) base[0] = sqrtf(expf(*curv) + s);
}

// ---------------------------------------------------------------- row x0 (bf16 h buffer, stride 4128, n=4099)
__global__ __launch_bounds__(256) void row_x0_bf_k(
    __bf16* __restrict__ buf, const float* __restrict__ curv)
{
    int row = blockIdx.x;
    __bf16* base = buf + (size_t)row * 4128;
    __shared__ float sb[4];
    float s = 0.f;
    for (int i = threadIdx.x; i < 4099; i += 256) { float t = (float)base[1 + i]; s += t * t; }
    s = blockSum256(s, sb);
    if (threadIdx.x == 0) base[0] = (__bf16)sqrtf(expf(*curv) + s);
    if (threadIdx.x < 28) base[4100 + threadIdx.x] = (__bf16)0.f;  // zero pad 4100..4127
}

// ---------------------------------------------------------------- weight convert + transpose
__global__ __launch_bounds__(256) void wt_k(
    const float* __restrict__ W, int K, int N,
    __bf16* __restrict__ Wt, int Kp)
{
    __shared__ float s[32][33];
    int tx = threadIdx.x & 31, ty = threadIdx.x >> 5;    // 32 x 8
    int k0 = blockIdx.x * 32, n0 = blockIdx.y * 32;
#pragma unroll
    for (int r = 0; r < 4; r++) {
        int k = k0 + ty + 8 * r, n = n0 + tx;
        s[ty + 8 * r][tx] = (k < K && n < N) ? W[(size_t)k * N + n] : 0.f;
    }
    __syncthreads();
#pragma unroll
    for (int r = 0; r < 4; r++) {
        int n = n0 + ty + 8 * r, k = k0 + tx;
        if (n < N) Wt[(size_t)n * Kp + k] = (__bf16)s[tx][ty + 8 * r];
    }
}

// ---------------------------------------------------------------- bf16 MFMA GEMM 128x128 (m97-style)
template<bool BIAS, bool GELU, bool SKIP, bool OUTBF>
__global__ __launch_bounds__(256) void mgemm_k(
    const __bf16* __restrict__ A, int lda,
    const __bf16* __restrict__ Bt, int ldb,
    const float* __restrict__ bias,
    const float* __restrict__ skip, int ldskip,
    void* __restrict__ Cout, int ldc,
    int N, int Kp)
{
    __shared__ __bf16 sA[128 * 32];
    __shared__ __bf16 sB[128 * 32];
    int tid = threadIdx.x;
    int w = tid >> 6, lane = tid & 63;
    int m0 = blockIdx.y * 128, n0 = blockIdx.x * 128;
    const __bf16* Ab = A + (size_t)m0 * lda;
    const __bf16* Bb = Bt + (size_t)n0 * ldb;

    f32x4 zero = {0.f, 0.f, 0.f, 0.f};
    f32x4 acc[4][4];
#pragma unroll
    for (int i = 0; i < 4; i++)
#pragma unroll
        for (int j = 0; j < 4; j++) acc[i][j] = zero;

    int mw = (w & 1) * 64, nw = (w >> 1) * 64;
    int lr = lane & 15, lq = lane >> 4;
    int fko = lq * 8;

    int r1 = tid >> 2, kk1 = (tid & 3) * 8;
    int r2 = (tid + 256) >> 2, kk2 = (tid & 3) * 8;
    __bf16* lA1 = &sA[(size_t)(w * 64) * 8];
    __bf16* lA2 = &sA[(size_t)(256 + w * 64) * 8];
    __bf16* lB1 = &sB[(size_t)(w * 64) * 8];
    __bf16* lB2 = &sB[(size_t)(256 + w * 64) * 8];

    for (int k0 = 0; k0 < Kp; k0 += 32) {
        g2l16(Ab + (size_t)r1 * lda + k0 + kk1, lA1);
        g2l16(Ab + (size_t)r2 * lda + k0 + kk2, lA2);
        g2l16(Bb + (size_t)r1 * ldb + k0 + kk1, lB1);
        g2l16(Bb + (size_t)r2 * ldb + k0 + kk2, lB2);
        __syncthreads();
        bf16x8 af[4], bf[4];
#pragma unroll
        for (int i = 0; i < 4; i++) af[i] = *(const bf16x8*)&sA[(mw + i * 16 + lr) * 32 + fko];
#pragma unroll
        for (int j = 0; j < 4; j++) bf[j] = *(const bf16x8*)&sB[(nw + j * 16 + lr) * 32 + fko];
#pragma unroll
        for (int i = 0; i < 4; i++)
#pragma unroll
            for (int j = 0; j < 4; j++)
                acc[i][j] = __builtin_amdgcn_mfma_f32_16x16x32_bf16(af[i], bf[j], acc[i][j], 0, 0, 0);
        __syncthreads();
    }

#pragma unroll
    for (int j = 0; j < 4; j++) {
        int n = n0 + nw + j * 16 + lr;
        if (n < N) {
            float bv = BIAS ? bias[n] : 0.f;
#pragma unroll
            for (int i = 0; i < 4; i++) {
#pragma unroll
                for (int r = 0; r < 4; r++) {
                    int m = m0 + mw + i * 16 + lq * 4 + r;
                    float v = acc[i][j][r] + bv;
                    if (GELU) v = 0.5f * v * (1.f + erff(v * 0.70710678118654752f));
                    if (SKIP) v += skip[(size_t)m * ldskip + n];
                    if (OUTBF) ((__bf16*)Cout)[(size_t)m * ldc + n] = (__bf16)v;
                    else       ((float*)Cout)[(size_t)m * ldc + n] = v;
                }
            }
        }
    }
}

// ---------------------------------------------------------------- bf16 MFMA GEMM 128x64 (2 blocks/CU for N=1024)
template<bool BIAS, bool GELU, bool SKIP>
__global__ __launch_bounds__(256) void mgemm64_k(
    const __bf16* __restrict__ A, int lda,
    const __bf16* __restrict__ Bt, int ldb,
    const float* __restrict__ bias,
    const float* __restrict__ skip, int ldskip,
    float* __restrict__ Cout, int ldc,
    int N, int Kp)
{
    __shared__ __bf16 sA[128 * 32];
    __shared__ __bf16 sB[64 * 32];
    int tid = threadIdx.x;
    int w = tid >> 6, lane = tid & 63;
    int m0 = blockIdx.y * 128, n0 = blockIdx.x * 64;
    const __bf16* Ab = A + (size_t)m0 * lda;
    const __bf16* Bb = Bt + (size_t)n0 * ldb;

    f32x4 zero = {0.f, 0.f, 0.f, 0.f};
    f32x4 acc[4][2];
#pragma unroll
    for (int i = 0; i < 4; i++) { acc[i][0] = zero; acc[i][1] = zero; }

    int mw = (w & 1) * 64, nw = (w >> 1) * 32;
    int lr = lane & 15, lq = lane >> 4;
    int fko = lq * 8;

    int rA = tid >> 2, kkA = (tid & 3) * 8;
    __bf16* lA1 = &sA[(size_t)(w * 64) * 8];
    __bf16* lA2 = &sA[(size_t)(256 + w * 64) * 8];
    __bf16* lB  = &sB[(size_t)(w * 64) * 8];

    for (int k0 = 0; k0 < Kp; k0 += 32) {
        g2l16(Ab + (size_t)rA * lda + k0 + kkA, lA1);
        g2l16(Ab + (size_t)(rA + 64) * lda + k0 + kkA, lA2);
        g2l16(Bb + (size_t)rA * ldb + k0 + kkA, lB);
        __syncthreads();
        bf16x8 af[4], bf[2];
#pragma unroll
        for (int i = 0; i < 4; i++) af[i] = *(const bf16x8*)&sA[(mw + i * 16 + lr) * 32 + fko];
#pragma unroll
        for (int j = 0; j < 2; j++) bf[j] = *(const bf16x8*)&sB[(nw + j * 16 + lr) * 32 + fko];
#pragma unroll
        for (int i = 0; i < 4; i++)
#pragma unroll
            for (int j = 0; j < 2; j++)
                acc[i][j] = __builtin_amdgcn_mfma_f32_16x16x32_bf16(af[i], bf[j], acc[i][j], 0, 0, 0);
        __syncthreads();
    }

#pragma unroll
    for (int j = 0; j < 2; j++) {
        int n = n0 + nw + j * 16 + lr;
        if (n < N) {
            float bv = BIAS ? bias[n] : 0.f;
#pragma unroll
            for (int i = 0; i < 4; i++) {
#pragma unroll
                for (int r = 0; r < 4; r++) {
                    int m = m0 + mw + i * 16 + lq * 4 + r;
                    float v = acc[i][j][r] + bv;
                    if (GELU) v = 0.5f * v * (1.f + erff(v * 0.70710678118654752f));
                    if (SKIP) v += skip[(size_t)m * ldskip + n];
                    Cout[(size_t)m * ldc + n] = v;
                }
            }
        }
    }
}

// ---------------------------------------------------------------- RoPE in-place(q) + Kb bf16 + q/k norms
__global__ __launch_bounds__(256) void rope_k(
    float* __restrict__ QKV, const float* __restrict__ curv,
    float* __restrict__ qt, float* __restrict__ kt,
    __bf16* __restrict__ Kb, __bf16* __restrict__ Obf)
{
    int row = blockIdx.x;              // b*T + t
    int b = row >> 11, t = row & (TT - 1);
    int wv = threadIdx.x >> 6, d = threadIdx.x & 63;
    int j = d & 31;
    float fr = (float)t * powf(10000.0f, -(float)(2 * j) / 64.0f);
    float cv = cosf(fr), sv = sinf(fr);
    float sgn = (d < 32) ? sv : -sv;
    for (int h = wv; h < HH; h += 4) {
        float Kh = expf(curv[h]);
        float* base = QKV + (size_t)row * 3072 + h * 64;
        float q = base[d], k = base[1024 + d];
        float qp = __shfl_xor(q, 32);
        float kp = __shfl_xor(k, 32);
        float qr = q * cv + qp * sgn;
        float kr = k * cv + kp * sgn;
        base[d] = qr;                         // q roped in place (fp32 for hi/lo split)
        size_t oidx = ((size_t)(b * HH + h) * TT + t);
        Kb[oidx * 64 + d] = (__bf16)kr;       // roped k, bf16 head-major
        float sq = qr * qr, sk = kr * kr;
#pragma unroll
        for (int o = 32; o; o >>= 1) {
            sq += __shfl_xor(sq, o);
            sk += __shfl_xor(sk, o);
        }
        if (d == 0) {
            qt[oidx] = sqrtf(Kh + sq);
            kt[oidx] = sqrtf(Kh + sk);
        }
    }
    if (threadIdx.x < 16) Obf[(size_t)row * 1056 + 1040 + threadIdx.x] = (__bf16)0.f;
}

// ---------------------------------------------------------------- V transpose -> Vtb bf16 [bh][d][t] + vt norms
__global__ __launch_bounds__(256) void vtrans_k(
    const float* __restrict__ QKV, const float* __restrict__ curv,
    __bf16* __restrict__ Vtb, float* __restrict__ vt)
{
    __shared__ float sT[64 * 65];
    int bh = blockIdx.y; int h = bh & (HH - 1); int b = bh >> 4;
    int t0 = blockIdx.x * 64;
    int tid = threadIdx.x, w = tid >> 6, lane = tid & 63;
    float Kh = expf(curv[h]);
    const float* vbase = QKV + (size_t)(b * TT + t0) * 3072 + 2048 + h * 64;
#pragma unroll 4
    for (int i = 0; i < 16; i++) {
        int tr = w * 16 + i;
        float v = vbase[(size_t)tr * 3072 + lane];
        sT[lane * 65 + tr] = v;
        float s = v * v;
#pragma unroll
        for (int o = 32; o; o >>= 1) s += __shfl_xor(s, o);
        if (lane == 0) vt[(size_t)bh * TT + t0 + tr] = sqrtf(Kh + s);
    }
    __syncthreads();
    int d = tid >> 2, seg = tid & 3;
    const float* r = &sT[d * 65 + seg * 16];
    bf16x8 o0, o1;
#pragma unroll
    for (int i = 0; i < 8; i++) { o0[i] = (__bf16)r[i]; o1[i] = (__bf16)r[8 + i]; }
    __bf16* dst = Vtb + ((size_t)bh * 64 + d) * TT + t0 + seg * 16;
    *(bf16x8*)dst = o0;
    *(bf16x8*)(dst + 8) = o1;
}

// ---------------------------------------------------------------- MFMA flash hyperbolic attention (v5)
// grid (x=bh, y=pi): flat id = pi*32+bh -> id%8 = bh%8 pins each bh to one XCD
// (K/V working set 2 MB/XCD < 4 MB L2). K/V staged from pre-converted bf16
// buffers via pure global_load_lds (LDS layout [ksp][quad][64][8] — conflict-
// free b128 frag reads and contiguous wave-order g2l16 writes).
__global__ __launch_bounds__(256, 4) void flash_k(
    const float* __restrict__ QKV,
    const __bf16* __restrict__ Kb, const __bf16* __restrict__ Vtb,
    const float* __restrict__ qt, const float* __restrict__ kt,
    const float* __restrict__ vt,
    const float* __restrict__ curv,
    __bf16* __restrict__ O)
{
    __shared__ __bf16 sK[4096];     // [ksp][quad][s=64][8 d]
    __shared__ __bf16 sVt[4096];    // [ksp][quad][d=64][8 s]
    __shared__ __bf16 sP[4 * 16 * 72];
    __shared__ float skt[64], svt[64];

    int bh = blockIdx.x; int h = bh & (HH - 1); int b = bh >> 4;
    int pi = blockIdx.y;                   // pair index 0..31
    float Kh = expf(curv[h]);
    float sqKh = sqrtf(Kh), msqK = -sqKh, invKh = 1.0f / Kh;
    const float* tok = QKV + (size_t)b * TT * 3072 + h * 64;  // roped q fp32
    const char* KbB = (const char*)Kb + (size_t)bh * TT * 128;
    const char* VtB = (const char*)Vtb + (size_t)bh * 64 * (TT * 2);
    const float* qtp = qt + (size_t)bh * TT;
    const float* ktp = kt + (size_t)bh * TT;
    const float* vtp = vt + (size_t)bh * TT;

    int tid = threadIdx.x;
    int w = tid >> 6, lane = tid & 63;
    int m = lane & 15, quad = lane >> 4;
    int qA = pi * 32, qB = (63 - pi) * 32;
    int myBase = (w < 2) ? (qA + 16 * w) : (qB + 16 * (w - 2));
    int myJmax = (myBase + 15) >> 6;
    int blockJmax = (qB + 31) >> 6;
    __bf16* sPw = &sP[w * 16 * 72];

    // Q fragments (hi + lo bf16), A-layout: A[m][k=quad*8+j+32*ks]
    bf16x8 qhi[2], qlo[2];
    {
        const float* qrow = tok + (size_t)(myBase + m) * 3072;
#pragma unroll
        for (int ks = 0; ks < 2; ks++) {
            const float* s = qrow + quad * 8 + 32 * ks;
            float4 f0 = *(const float4*)s;
            float4 f1 = *(const float4*)(s + 4);
            float fa[8] = {f0.x, f0.y, f0.z, f0.w, f1.x, f1.y, f1.z, f1.w};
#pragma unroll
            for (int jj = 0; jj < 8; jj++) {
                __bf16 hv = (__bf16)fa[jj];
                qhi[ks][jj] = hv;
                qlo[ks][jj] = (__bf16)(fa[jj] - (float)hv);
            }
        }
    }
    float qtv[4]; int qg[4];
#pragma unroll
    for (int r = 0; r < 4; r++) { qg[r] = myBase + quad * 4 + r; qtv[r] = qtp[qg[r]]; }

    f32x4 zero = {0.f, 0.f, 0.f, 0.f};
    f32x4 accO[4];
#pragma unroll
    for (int nt = 0; nt < 4; nt++) accO[nt] = zero;
    float lsumr[4] = {}, o0r[4] = {};

    char* sKb  = (char*)sK  + w * 1024;
    char* sVb  = (char*)sVt + w * 1024;

    for (int j = 0; j <= blockJmax; ++j) {
        int sb = j << 6;
        __syncthreads();
        // ---- stage K/V tiles: 4 pure g2l16 per thread ----
        {
            const char* kg = KbB + (size_t)(sb + lane) * 128 + w * 16;
            g2l16(kg,      sKb);
            g2l16(kg + 64, sKb + 4096);
            const char* vg = VtB + (size_t)lane * (TT * 2) + sb * 2 + w * 16;
            g2l16(vg,      sVb);
            g2l16(vg + 64, sVb + 4096);
        }
        if (tid < 64) skt[tid] = ktp[sb + tid];
        else if (tid < 128) svt[tid - 64] = vtp[sb + tid - 64];
        __syncthreads();

        if (j > myJmax) continue;

        // ---- QK^T: S[16 x 64] ----
        f32x4 accS[4];
#pragma unroll
        for (int nt = 0; nt < 4; nt++) accS[nt] = zero;
#pragma unroll
        for (int nt = 0; nt < 4; nt++) {
#pragma unroll
            for (int ksp = 0; ksp < 2; ksp++) {
                bf16x8 bk = *(const bf16x8*)&sK[((ksp * 4 + quad) * 64 + nt * 16 + m) * 8];
                accS[nt] = __builtin_amdgcn_mfma_f32_16x16x32_bf16(qhi[ksp], bk, accS[nt], 0, 0, 0);
                accS[nt] = __builtin_amdgcn_mfma_f32_16x16x32_bf16(qlo[ksp], bk, accS[nt], 0, 0, 0);
            }
        }
        // ---- score epilogue: hyperbolic logit -> p (bf16), lsum/o0 accum ----
#pragma unroll
        for (int nt = 0; nt < 4; nt++) {
            int col = nt * 16 + m;
            int sglob = sb + col;
            float ktv = skt[col], vtv = svt[col];
#pragma unroll
            for (int r = 0; r < 4; r++) {
                float dot = accS[nt][r];
                float rdiff = fmaf(qtv[r], ktv, -dot);          // qt*kt - q.k
                float ratio = fmaxf(rdiff * invKh, 1.0f + 1e-7f);
                float y = ratio + sqrtf(fmaf(ratio, ratio, -1.0f));
                float pv = exp2f(msqK * log2f(y));              // exp(-sqrt(K)*acosh)
                float p = (sglob <= qg[r]) ? pv : 0.0f;
                __bf16 pb = (__bf16)p;
                float pf = (float)pb;                           // rounded, consistent with PV
                lsumr[r] += pf;
                o0r[r] += pf * vtv;
                sPw[(quad * 4 + r) * 72 + col] = pb;
            }
        }
        __asm__ volatile("s_waitcnt lgkmcnt(0)" ::: "memory");
        // ---- PV: O += P @ V ----
#pragma unroll
        for (int ksp = 0; ksp < 2; ksp++) {
            bf16x8 aP = *(const bf16x8*)&sPw[m * 72 + ksp * 32 + quad * 8];
#pragma unroll
            for (int nt = 0; nt < 4; nt++) {
                bf16x8 bV = *(const bf16x8*)&sVt[((ksp * 4 + quad) * 64 + nt * 16 + m) * 8];
                accO[nt] = __builtin_amdgcn_mfma_f32_16x16x32_bf16(aP, bV, accO[nt], 0, 0, 0);
            }
        }
    }

    // ---- final: reduce lsum/o0 over the 16 col-lanes, normalize, write ----
#pragma unroll
    for (int r = 0; r < 4; r++) {
#pragma unroll
        for (int off = 1; off < 16; off <<= 1) {
            lsumr[r] += __shfl_xor(lsumr[r], off);
            o0r[r]   += __shfl_xor(o0r[r], off);
        }
    }
#pragma unroll
    for (int r = 0; r < 4; r++) {
        float inv = 1.0f / lsumr[r];
        float o0f = o0r[r] * inv;
        float ov[4]; float part = 0.f;
#pragma unroll
        for (int nt = 0; nt < 4; nt++) { float t = accO[nt][r] * inv; ov[nt] = t; part += t * t; }
        part += __shfl_xor(part, 1);
        part += __shfl_xor(part, 2);
        part += __shfl_xor(part, 4);
        part += __shfl_xor(part, 8);
        float scale = sqKh * rsqrtf(fmaxf(o0f * o0f - part, 1e-12f));
        size_t orow = (size_t)(b * TT + qg[r]) * 1056 + h * 65;
        if (m == 0) O[orow] = (__bf16)(o0f * scale);
#pragma unroll
        for (int nt = 0; nt < 4; nt++) O[orow + 1 + nt * 16 + m] = (__bf16)(ov[nt] * scale);
    }
}

// ---------------------------------------------------------------- launch
extern "C" void kernel_launch(void* const* d_in, const int* in_sizes, int n_in,
                              void* d_out, int out_size, void* d_ws, size_t ws_size,
                              hipStream_t stream) {
    const float* x    = (const float*)d_in[0];
    const float* bc   = (const float*)d_in[1];
    const float* mc   = (const float*)d_in[2];
    const float* ac   = (const float*)d_in[3];
    const float* w_qkv = (const float*)d_in[4];
    const float* w_ap  = (const float*)d_in[5];
    const float* b_ap  = (const float*)d_in[6];
    const float* w_me  = (const float*)d_in[7];
    const float* b_me  = (const float*)d_in[8];
    const float* w_ms  = (const float*)d_in[9];
    const float* b_ms  = (const float*)d_in[10];
    const float* lnw  = (const float*)d_in[11];
    const float* lnb  = (const float*)d_in[12];
    float* out = (float*)d_out;
    float* ws  = (float*)d_ws;

    // workspace (floats), total ~94.4 MB — same footprint as R4.
    // R: qkv fp32 (steps 2-4); X2 fp32 aliases [0..4.19M) from step 5;
    //    h_bf bf16 aliases [4.19M..12.65M) from step 7.
    float* R      = ws;
    float* qkvbuf = R;
    float* X2     = R;
    __bf16* h_bf  = (__bf16*)(R + 4194304);
    float* p      = R + 12648448;
    __bf16* ln_bf = (__bf16*)p;  p += 2162688;   // M*1056 bf16
    __bf16* o_bf  = (__bf16*)p;  p += 2162688;   // M*1056 bf16
    __bf16* qkvT  = (__bf16*)p;  p += 1622016;   // 3072*1056 bf16
    __bf16* apT   = (__bf16*)p;  p += 540672;    // 1024*1056 bf16
    float*  meT_f = p;           p += 2164272;   // 4099*1056 bf16 (after flash)
    float*  msT_f = p;           p += 2113536;   // 1024*4128 bf16 (after flash)
    float* Qt = p;               p += 2 * HH * TT;
    float* Kt = p;               p += 2 * HH * TT;
    float* Vt = p;
    __bf16* meT = (__bf16*)meT_f;
    __bf16* msT = (__bf16*)msT_f;
    __bf16* Kb  = (__bf16*)meT_f;   // 32*2048*64 bf16 = 2,097,152 fl <= meT slot; dead before wt_k(meT)
    __bf16* Vtb = (__bf16*)msT_f;   // same size      <= msT slot; dead before wt_k(msT)

    // 0. weight transposes needed before flash
    wt_k<<<dim3(33, 96),  256, 0, stream>>>(w_qkv, 1025, 3072, qkvT, 1056);
    wt_k<<<dim3(33, 32),  256, 0, stream>>>(w_ap,  1040, 1024, apT,  1056);

    // 1. ln1 = block_norm(project(x)) -> bf16
    block_norm_bf_k<<<MM, 256, 0, stream>>>(x, 1024, ln_bf, lnw, lnb, bc);
    // 2. qkv = ln1 @ w_qkv -> fp32 (M,3072)
    mgemm_k<false, false, false, false><<<dim3(24, 32), 256, 0, stream>>>(
        ln_bf, 1056, qkvT, 1056, nullptr, nullptr, 0, qkvbuf, 3072, 3072, 1056);
    // 3a. RoPE (q in place fp32, Kb bf16) + q/k norms + o_bf pad
    rope_k<<<MM, 256, 0, stream>>>(qkvbuf, ac, Qt, Kt, Kb, o_bf);
    // 3b. V transpose -> Vtb bf16 + v norms
    vtrans_k<<<dim3(32, 32), 256, 0, stream>>>(qkvbuf, ac, Vtb, Vt);
    // 4. MFMA flash attention -> o_t bf16 (M,1056)
    flash_k<<<dim3(2 * HH, 32), 256, 0, stream>>>(qkvbuf, Kb, Vtb, Qt, Kt, Vt, ac, o_bf);
    // 0b. remaining weight transposes (into the slots Kb/Vtb just vacated)
    wt_k<<<dim3(33, 129), 256, 0, stream>>>(w_me,  1025, 4099, meT, 1056);
    wt_k<<<dim3(129, 32), 256, 0, stream>>>(w_ms,  4100, 1024, msT, 4128);
    // 5. lx2[...,1:] = x + o_t @ w_attn_proj + b -> X2 fp32
    mgemm64_k<true, false, true><<<dim3(16, 32), 256, 0, stream>>>(
        o_bf, 1056, apT, 1056, b_ap, x, 1024, X2, 1024, 1024, 1056);
    // 6. ln2 = block_norm(lx2) -> bf16
    block_norm_bf_k<<<MM, 256, 0, stream>>>(X2, 1024, ln_bf, lnw, lnb, bc);
    // 7. h = gelu(ln2 @ w_mlp_expand + b) -> bf16
    mgemm_k<true, true, false, true><<<dim3(33, 32), 256, 0, stream>>>(
        ln_bf, 1056, meT, 1056, b_me, nullptr, 0, (void*)(h_bf + 1), 4128, 4099, 1056);
    // 8. h x0 column + pad zero
    row_x0_bf_k<<<MM, 256, 0, stream>>>(h_bf, mc);
    // 9. out[...,1:] = lx2[...,1:] + h @ w_mlp_shrink + b
    mgemm64_k<true, false, true><<<dim3(16, 32), 256, 0, stream>>>(
        h_bf, 4128, msT, 4128, b_ms, X2, 1024, out + 1, 1025, 1024, 4128);
    // 10. out[...,0]
    row_x0_k<<<MM, 256, 0, stream>>>(out, 1025, 1024, bc);
}

// Round 7
// 531.950 us; speedup vs baseline: 11.4804x; 1.0956x over previous
//
#include <hip/hip_runtime.h>
#include <math.h>

// Problem constants: B=2, T=2048, E=1024, H=16, D=64; M = B*T = 4096
#define MM   4096
#define TT   2048
#define HH   16

typedef __bf16 bf16x8 __attribute__((ext_vector_type(8)));
typedef float f32x4 __attribute__((ext_vector_type(4)));

// async global->LDS, 16B per lane; LDS dest = wave-uniform base + lane*16
__device__ __forceinline__ void g2l16(const void* g, void* l) {
    __builtin_amdgcn_global_load_lds(
        (__attribute__((address_space(1))) void*)g,
        (__attribute__((address_space(3))) void*)l, 16, 0, 0);
}

// ---- raw transcendentals (guarded; libm fallback). Without -ffast-math the
// libm versions lower to multi-instruction OCML guard sequences — 3-4x cost.
#if __has_builtin(__builtin_amdgcn_exp2f)
__device__ __forceinline__ float fexp2(float x) { return __builtin_amdgcn_exp2f(x); }
#else
__device__ __forceinline__ float fexp2(float x) { return exp2f(x); }
#endif
#if __has_builtin(__builtin_amdgcn_logf)
__device__ __forceinline__ float flog2(float x) { return __builtin_amdgcn_logf(x); }
#else
__device__ __forceinline__ float flog2(float x) { return log2f(x); }
#endif
#if __has_builtin(__builtin_amdgcn_sqrtf)
__device__ __forceinline__ float fsqrt_(float x) { return __builtin_amdgcn_sqrtf(x); }
#else
__device__ __forceinline__ float fsqrt_(float x) { return sqrtf(x); }
#endif
#if __has_builtin(__builtin_amdgcn_rcpf)
__device__ __forceinline__ float frcp_(float x) { return __builtin_amdgcn_rcpf(x); }
#else
__device__ __forceinline__ float frcp_(float x) { return 1.0f / x; }
#endif
#if __has_builtin(__builtin_amdgcn_rsqf)
__device__ __forceinline__ float frsq_(float x) { return __builtin_amdgcn_rsqf(x); }
#else
__device__ __forceinline__ float frsq_(float x) { return rsqrtf(x); }
#endif

// ---------------------------------------------------------------- reductions
__device__ __forceinline__ float blockSum256(float v, volatile float* sb) {
    int lane = threadIdx.x & 63, w = threadIdx.x >> 6;
#pragma unroll
    for (int o = 32; o; o >>= 1) v += __shfl_xor(v, o);
    if (lane == 0) sb[w] = v;
    __syncthreads();
    v = sb[0] + sb[1] + sb[2] + sb[3];
    __syncthreads();
    return v;
}

// ---------------------------------------------------------------- block_norm -> bf16 (1056-wide, zero pad)
__global__ __launch_bounds__(256) void block_norm_bf_k(
    const float* __restrict__ in, int ld,
    __bf16* __restrict__ out,
    const float* __restrict__ lw, const float* __restrict__ lb,
    const float* __restrict__ curv)
{
    int row = blockIdx.x;
    const float* x = in + (size_t)row * ld;
    __bf16* o = out + (size_t)row * 1056;
    __shared__ float sb[4];
    int tid = threadIdx.x;
    float v[4]; float s1 = 0.f, s2 = 0.f;
#pragma unroll
    for (int r = 0; r < 4; r++) {
        float t = x[tid + 256 * r];
        v[r] = t; s1 += t; s2 += t * t;
    }
    s1 = blockSum256(s1, sb);
    s2 = blockSum256(s2, sb);
    float mean = s1 * (1.f / 1024.f);
    float var  = s2 * (1.f / 1024.f) - mean * mean;
    float rs = rsqrtf(var + 1e-5f);
    float y[4]; float ssq = 0.f;
#pragma unroll
    for (int r = 0; r < 4; r++) {
        int i = tid + 256 * r;
        float t = (v[r] - mean) * rs * lw[i] + lb[i];
        y[r] = t; ssq += t * t;
    }
    ssq = blockSum256(ssq, sb);
#pragma unroll
    for (int r = 0; r < 4; r++) o[1 + tid + 256 * r] = (__bf16)y[r];
    if (tid == 0) o[0] = (__bf16)sqrtf(expf(*curv) + ssq);
    if (tid < 31) o[1025 + tid] = (__bf16)0.f;   // zero pad cols 1025..1055
}

// ---------------------------------------------------------------- row x0 (fp32, final output)
__global__ __launch_bounds__(256) void row_x0_k(
    float* __restrict__ buf, int stride, int n, const float* __restrict__ curv)
{
    int row = blockIdx.x;
    float* base = buf + (size_t)row * stride;
    __shared__ float sb[4];
    float s = 0.f;
    for (int i = threadIdx.x; i < n; i += 256) { float t = base[1 + i]; s += t * t; }
    s = blockSum256(s, sb);
    if (threadIdx.x == 0) base[0] = sqrtf(expf(*curv) + s);
}

// ---------------------------------------------------------------- row x0 (bf16 h buffer, stride 4128, n=4099)
__global__ __launch_bounds__(256) void row_x0_bf_k(
    __bf16* __restrict__ buf, const float* __restrict__ curv)
{
    int row = blockIdx.x;
    __bf16* base = buf + (size_t)row * 4128;
    __shared__ float sb[4];
    float s = 0.f;
    for (int i = threadIdx.x; i < 4099; i += 256) { float t = (float)base[1 + i]; s += t * t; }
    s = blockSum256(s, sb);
    if (threadIdx.x == 0) base[0] = (__bf16)sqrtf(expf(*curv) + s);
    if (threadIdx.x < 28) base[4100 + threadIdx.x] = (__bf16)0.f;  // zero pad 4100..4127
}

// ---------------------------------------------------------------- weight convert + transpose
__global__ __launch_bounds__(256) void wt_k(
    const float* __restrict__ W, int K, int N,
    __bf16* __restrict__ Wt, int Kp)
{
    __shared__ float s[32][33];
    int tx = threadIdx.x & 31, ty = threadIdx.x >> 5;    // 32 x 8
    int k0 = blockIdx.x * 32, n0 = blockIdx.y * 32;
#pragma unroll
    for (int r = 0; r < 4; r++) {
        int k = k0 + ty + 8 * r, n = n0 + tx;
        s[ty + 8 * r][tx] = (k < K && n < N) ? W[(size_t)k * N + n] : 0.f;
    }
    __syncthreads();
#pragma unroll
    for (int r = 0; r < 4; r++) {
        int n = n0 + ty + 8 * r, k = k0 + tx;
        if (n < N) Wt[(size_t)n * Kp + k] = (__bf16)s[tx][ty + 8 * r];
    }
}

// ---------------------------------------------------------------- bf16 MFMA GEMM 128x128 (m97-style)
template<bool BIAS, bool GELU, bool SKIP, bool OUTBF>
__global__ __launch_bounds__(256) void mgemm_k(
    const __bf16* __restrict__ A, int lda,
    const __bf16* __restrict__ Bt, int ldb,
    const float* __restrict__ bias,
    const float* __restrict__ skip, int ldskip,
    void* __restrict__ Cout, int ldc,
    int N, int Kp)
{
    __shared__ __bf16 sA[128 * 32];
    __shared__ __bf16 sB[128 * 32];
    int tid = threadIdx.x;
    int w = tid >> 6, lane = tid & 63;
    int m0 = blockIdx.y * 128, n0 = blockIdx.x * 128;
    const __bf16* Ab = A + (size_t)m0 * lda;
    const __bf16* Bb = Bt + (size_t)n0 * ldb;

    f32x4 zero = {0.f, 0.f, 0.f, 0.f};
    f32x4 acc[4][4];
#pragma unroll
    for (int i = 0; i < 4; i++)
#pragma unroll
        for (int j = 0; j < 4; j++) acc[i][j] = zero;

    int mw = (w & 1) * 64, nw = (w >> 1) * 64;
    int lr = lane & 15, lq = lane >> 4;
    int fko = lq * 8;

    int r1 = tid >> 2, kk1 = (tid & 3) * 8;
    int r2 = (tid + 256) >> 2, kk2 = (tid & 3) * 8;
    __bf16* lA1 = &sA[(size_t)(w * 64) * 8];
    __bf16* lA2 = &sA[(size_t)(256 + w * 64) * 8];
    __bf16* lB1 = &sB[(size_t)(w * 64) * 8];
    __bf16* lB2 = &sB[(size_t)(256 + w * 64) * 8];

    for (int k0 = 0; k0 < Kp; k0 += 32) {
        g2l16(Ab + (size_t)r1 * lda + k0 + kk1, lA1);
        g2l16(Ab + (size_t)r2 * lda + k0 + kk2, lA2);
        g2l16(Bb + (size_t)r1 * ldb + k0 + kk1, lB1);
        g2l16(Bb + (size_t)r2 * ldb + k0 + kk2, lB2);
        __syncthreads();
        bf16x8 af[4], bf[4];
#pragma unroll
        for (int i = 0; i < 4; i++) af[i] = *(const bf16x8*)&sA[(mw + i * 16 + lr) * 32 + fko];
#pragma unroll
        for (int j = 0; j < 4; j++) bf[j] = *(const bf16x8*)&sB[(nw + j * 16 + lr) * 32 + fko];
#pragma unroll
        for (int i = 0; i < 4; i++)
#pragma unroll
            for (int j = 0; j < 4; j++)
                acc[i][j] = __builtin_amdgcn_mfma_f32_16x16x32_bf16(af[i], bf[j], acc[i][j], 0, 0, 0);
        __syncthreads();
    }

#pragma unroll
    for (int j = 0; j < 4; j++) {
        int n = n0 + nw + j * 16 + lr;
        if (n < N) {
            float bv = BIAS ? bias[n] : 0.f;
#pragma unroll
            for (int i = 0; i < 4; i++) {
#pragma unroll
                for (int r = 0; r < 4; r++) {
                    int m = m0 + mw + i * 16 + lq * 4 + r;
                    float v = acc[i][j][r] + bv;
                    if (GELU) v = 0.5f * v * (1.f + erff(v * 0.70710678118654752f));
                    if (SKIP) v += skip[(size_t)m * ldskip + n];
                    if (OUTBF) ((__bf16*)Cout)[(size_t)m * ldc + n] = (__bf16)v;
                    else       ((float*)Cout)[(size_t)m * ldc + n] = v;
                }
            }
        }
    }
}

// ---------------------------------------------------------------- bf16 MFMA GEMM 128x64 (2 blocks/CU for N=1024)
template<bool BIAS, bool GELU, bool SKIP>
__global__ __launch_bounds__(256) void mgemm64_k(
    const __bf16* __restrict__ A, int lda,
    const __bf16* __restrict__ Bt, int ldb,
    const float* __restrict__ bias,
    const float* __restrict__ skip, int ldskip,
    float* __restrict__ Cout, int ldc,
    int N, int Kp)
{
    __shared__ __bf16 sA[128 * 32];
    __shared__ __bf16 sB[64 * 32];
    int tid = threadIdx.x;
    int w = tid >> 6, lane = tid & 63;
    int m0 = blockIdx.y * 128, n0 = blockIdx.x * 64;
    const __bf16* Ab = A + (size_t)m0 * lda;
    const __bf16* Bb = Bt + (size_t)n0 * ldb;

    f32x4 zero = {0.f, 0.f, 0.f, 0.f};
    f32x4 acc[4][2];
#pragma unroll
    for (int i = 0; i < 4; i++) { acc[i][0] = zero; acc[i][1] = zero; }

    int mw = (w & 1) * 64, nw = (w >> 1) * 32;
    int lr = lane & 15, lq = lane >> 4;
    int fko = lq * 8;

    int rA = tid >> 2, kkA = (tid & 3) * 8;
    __bf16* lA1 = &sA[(size_t)(w * 64) * 8];
    __bf16* lA2 = &sA[(size_t)(256 + w * 64) * 8];
    __bf16* lB  = &sB[(size_t)(w * 64) * 8];

    for (int k0 = 0; k0 < Kp; k0 += 32) {
        g2l16(Ab + (size_t)rA * lda + k0 + kkA, lA1);
        g2l16(Ab + (size_t)(rA + 64) * lda + k0 + kkA, lA2);
        g2l16(Bb + (size_t)rA * ldb + k0 + kkA, lB);
        __syncthreads();
        bf16x8 af[4], bf[2];
#pragma unroll
        for (int i = 0; i < 4; i++) af[i] = *(const bf16x8*)&sA[(mw + i * 16 + lr) * 32 + fko];
#pragma unroll
        for (int j = 0; j < 2; j++) bf[j] = *(const bf16x8*)&sB[(nw + j * 16 + lr) * 32 + fko];
#pragma unroll
        for (int i = 0; i < 4; i++)
#pragma unroll
            for (int j = 0; j < 2; j++)
                acc[i][j] = __builtin_amdgcn_mfma_f32_16x16x32_bf16(af[i], bf[j], acc[i][j], 0, 0, 0);
        __syncthreads();
    }

#pragma unroll
    for (int j = 0; j < 2; j++) {
        int n = n0 + nw + j * 16 + lr;
        if (n < N) {
            float bv = BIAS ? bias[n] : 0.f;
#pragma unroll
            for (int i = 0; i < 4; i++) {
#pragma unroll
                for (int r = 0; r < 4; r++) {
                    int m = m0 + mw + i * 16 + lq * 4 + r;
                    float v = acc[i][j][r] + bv;
                    if (GELU) v = 0.5f * v * (1.f + erff(v * 0.70710678118654752f));
                    if (SKIP) v += skip[(size_t)m * ldskip + n];
                    Cout[(size_t)m * ldc + n] = v;
                }
            }
        }
    }
}

// ---------------------------------------------------------------- RoPE in-place(q) + Kb bf16 + q/k norms
__global__ __launch_bounds__(256) void rope_k(
    float* __restrict__ QKV, const float* __restrict__ curv,
    float* __restrict__ qt, float* __restrict__ kt,
    __bf16* __restrict__ Kb, __bf16* __restrict__ Obf)
{
    int row = blockIdx.x;              // b*T + t
    int b = row >> 11, t = row & (TT - 1);
    int wv = threadIdx.x >> 6, d = threadIdx.x & 63;
    int j = d & 31;
    float fr = (float)t * powf(10000.0f, -(float)(2 * j) / 64.0f);
    float cv = cosf(fr), sv = sinf(fr);
    float sgn = (d < 32) ? sv : -sv;
    for (int h = wv; h < HH; h += 4) {
        float Kh = expf(curv[h]);
        float* base = QKV + (size_t)row * 3072 + h * 64;
        float q = base[d], k = base[1024 + d];
        float qp = __shfl_xor(q, 32);
        float kp = __shfl_xor(k, 32);
        float qr = q * cv + qp * sgn;
        float kr = k * cv + kp * sgn;
        base[d] = qr;                         // q roped in place (fp32 for hi/lo split)
        size_t oidx = ((size_t)(b * HH + h) * TT + t);
        Kb[oidx * 64 + d] = (__bf16)kr;       // roped k, bf16 head-major
        float sq = qr * qr, sk = kr * kr;
#pragma unroll
        for (int o = 32; o; o >>= 1) {
            sq += __shfl_xor(sq, o);
            sk += __shfl_xor(sk, o);
        }
        if (d == 0) {
            qt[oidx] = sqrtf(Kh + sq);
            kt[oidx] = sqrtf(Kh + sk);
        }
    }
    if (threadIdx.x < 16) Obf[(size_t)row * 1056 + 1040 + threadIdx.x] = (__bf16)0.f;
}

// ---------------------------------------------------------------- V transpose -> Vtb bf16 [bh][d][t] + vt norms
__global__ __launch_bounds__(256) void vtrans_k(
    const float* __restrict__ QKV, const float* __restrict__ curv,
    __bf16* __restrict__ Vtb, float* __restrict__ vt)
{
    __shared__ float sT[64 * 65];
    int bh = blockIdx.y; int h = bh & (HH - 1); int b = bh >> 4;
    int t0 = blockIdx.x * 64;
    int tid = threadIdx.x, w = tid >> 6, lane = tid & 63;
    float Kh = expf(curv[h]);
    const float* vbase = QKV + (size_t)(b * TT + t0) * 3072 + 2048 + h * 64;
#pragma unroll 4
    for (int i = 0; i < 16; i++) {
        int tr = w * 16 + i;
        float v = vbase[(size_t)tr * 3072 + lane];
        sT[lane * 65 + tr] = v;
        float s = v * v;
#pragma unroll
        for (int o = 32; o; o >>= 1) s += __shfl_xor(s, o);
        if (lane == 0) vt[(size_t)bh * TT + t0 + tr] = sqrtf(Kh + s);
    }
    __syncthreads();
    int d = tid >> 2, seg = tid & 3;
    const float* r = &sT[d * 65 + seg * 16];
    bf16x8 o0, o1;
#pragma unroll
    for (int i = 0; i < 8; i++) { o0[i] = (__bf16)r[i]; o1[i] = (__bf16)r[8 + i]; }
    __bf16* dst = Vtb + ((size_t)bh * 64 + d) * TT + t0 + seg * 16;
    *(bf16x8*)dst = o0;
    *(bf16x8*)(dst + 8) = o1;
}

// ---------------------------------------------------------------- MFMA flash hyperbolic attention (v6)
// v5 + raw transcendentals in the score chain (v_sqrt/v_log/v_exp direct —
// libm emits guarded OCML sequences without -ffast-math) and unrounded-p
// lsum/o0 accumulation (normalization scale error cancels in the Lorentz
// rescale, which is linear in o).
__global__ __launch_bounds__(256, 4) void flash_k(
    const float* __restrict__ QKV,
    const __bf16* __restrict__ Kb, const __bf16* __restrict__ Vtb,
    const float* __restrict__ qt, const float* __restrict__ kt,
    const float* __restrict__ vt,
    const float* __restrict__ curv,
    __bf16* __restrict__ O)
{
    __shared__ __bf16 sK[4096];     // [ksp][quad][s=64][8 d]
    __shared__ __bf16 sVt[4096];    // [ksp][quad][d=64][8 s]
    __shared__ __bf16 sP[4 * 16 * 72];
    __shared__ float skt[64], svt[64];

    int bh = blockIdx.x; int h = bh & (HH - 1); int b = bh >> 4;
    int pi = blockIdx.y;                   // pair index 0..31
    float Kh = expf(curv[h]);
    float sqKh = sqrtf(Kh), msqK = -sqKh, invKh = 1.0f / Kh;
    const float* tok = QKV + (size_t)b * TT * 3072 + h * 64;  // roped q fp32
    const char* KbB = (const char*)Kb + (size_t)bh * TT * 128;
    const char* VtB = (const char*)Vtb + (size_t)bh * 64 * (TT * 2);
    const float* qtp = qt + (size_t)bh * TT;
    const float* ktp = kt + (size_t)bh * TT;
    const float* vtp = vt + (size_t)bh * TT;

    int tid = threadIdx.x;
    int w = tid >> 6, lane = tid & 63;
    int m = lane & 15, quad = lane >> 4;
    int qA = pi * 32, qB = (63 - pi) * 32;
    int myBase = (w < 2) ? (qA + 16 * w) : (qB + 16 * (w - 2));
    int myJmax = (myBase + 15) >> 6;
    int blockJmax = (qB + 31) >> 6;
    __bf16* sPw = &sP[w * 16 * 72];

    // Q fragments (hi + lo bf16), A-layout: A[m][k=quad*8+j+32*ks]
    bf16x8 qhi[2], qlo[2];
    {
        const float* qrow = tok + (size_t)(myBase + m) * 3072;
#pragma unroll
        for (int ks = 0; ks < 2; ks++) {
            const float* s = qrow + quad * 8 + 32 * ks;
            float4 f0 = *(const float4*)s;
            float4 f1 = *(const float4*)(s + 4);
            float fa[8] = {f0.x, f0.y, f0.z, f0.w, f1.x, f1.y, f1.z, f1.w};
#pragma unroll
            for (int jj = 0; jj < 8; jj++) {
                __bf16 hv = (__bf16)fa[jj];
                qhi[ks][jj] = hv;
                qlo[ks][jj] = (__bf16)(fa[jj] - (float)hv);
            }
        }
    }
    float qtv[4]; int qg[4];
#pragma unroll
    for (int r = 0; r < 4; r++) { qg[r] = myBase + quad * 4 + r; qtv[r] = qtp[qg[r]]; }

    f32x4 zero = {0.f, 0.f, 0.f, 0.f};
    f32x4 accO[4];
#pragma unroll
    for (int nt = 0; nt < 4; nt++) accO[nt] = zero;
    float lsumr[4] = {}, o0r[4] = {};

    char* sKb  = (char*)sK  + w * 1024;
    char* sVb  = (char*)sVt + w * 1024;

    for (int j = 0; j <= blockJmax; ++j) {
        int sb = j << 6;
        __syncthreads();
        // ---- stage K/V tiles: 4 pure g2l16 per thread ----
        {
            const char* kg = KbB + (size_t)(sb + lane) * 128 + w * 16;
            g2l16(kg,      sKb);
            g2l16(kg + 64, sKb + 4096);
            const char* vg = VtB + (size_t)lane * (TT * 2) + sb * 2 + w * 16;
            g2l16(vg,      sVb);
            g2l16(vg + 64, sVb + 4096);
        }
        if (tid < 64) skt[tid] = ktp[sb + tid];
        else if (tid < 128) svt[tid - 64] = vtp[sb + tid - 64];
        __syncthreads();

        if (j > myJmax) continue;

        // ---- QK^T: S[16 x 64] ----
        f32x4 accS[4];
#pragma unroll
        for (int nt = 0; nt < 4; nt++) accS[nt] = zero;
#pragma unroll
        for (int nt = 0; nt < 4; nt++) {
#pragma unroll
            for (int ksp = 0; ksp < 2; ksp++) {
                bf16x8 bk = *(const bf16x8*)&sK[((ksp * 4 + quad) * 64 + nt * 16 + m) * 8];
                accS[nt] = __builtin_amdgcn_mfma_f32_16x16x32_bf16(qhi[ksp], bk, accS[nt], 0, 0, 0);
                accS[nt] = __builtin_amdgcn_mfma_f32_16x16x32_bf16(qlo[ksp], bk, accS[nt], 0, 0, 0);
            }
        }
        // ---- score epilogue: hyperbolic logit -> p, raw transcendentals ----
#pragma unroll
        for (int nt = 0; nt < 4; nt++) {
            int col = nt * 16 + m;
            int sglob = sb + col;
            float ktv = skt[col], vtv = svt[col];
#pragma unroll
            for (int r = 0; r < 4; r++) {
                float dot = accS[nt][r];
                float rdiff = fmaf(qtv[r], ktv, -dot);          // qt*kt - q.k
                float ratio = fmaxf(rdiff * invKh, 1.0f + 1e-7f);
                float y = ratio + fsqrt_(fmaf(ratio, ratio, -1.0f));
                float pv = fexp2(msqK * flog2(y));              // exp(-sqrt(K)*acosh)
                float p = (sglob <= qg[r]) ? pv : 0.0f;
                lsumr[r] += p;
                o0r[r] = fmaf(p, vtv, o0r[r]);
                sPw[(quad * 4 + r) * 72 + col] = (__bf16)p;
            }
        }
        __asm__ volatile("s_waitcnt lgkmcnt(0)" ::: "memory");
        // ---- PV: O += P @ V ----
#pragma unroll
        for (int ksp = 0; ksp < 2; ksp++) {
            bf16x8 aP = *(const bf16x8*)&sPw[m * 72 + ksp * 32 + quad * 8];
#pragma unroll
            for (int nt = 0; nt < 4; nt++) {
                bf16x8 bV = *(const bf16x8*)&sVt[((ksp * 4 + quad) * 64 + nt * 16 + m) * 8];
                accO[nt] = __builtin_amdgcn_mfma_f32_16x16x32_bf16(aP, bV, accO[nt], 0, 0, 0);
            }
        }
    }

    // ---- final: reduce lsum/o0 over the 16 col-lanes, normalize, write ----
#pragma unroll
    for (int r = 0; r < 4; r++) {
#pragma unroll
        for (int off = 1; off < 16; off <<= 1) {
            lsumr[r] += __shfl_xor(lsumr[r], off);
            o0r[r]   += __shfl_xor(o0r[r], off);
        }
    }
#pragma unroll
    for (int r = 0; r < 4; r++) {
        float inv = frcp_(lsumr[r]);
        float o0f = o0r[r] * inv;
        float ov[4]; float part = 0.f;
#pragma unroll
        for (int nt = 0; nt < 4; nt++) { float t = accO[nt][r] * inv; ov[nt] = t; part += t * t; }
        part += __shfl_xor(part, 1);
        part += __shfl_xor(part, 2);
        part += __shfl_xor(part, 4);
        part += __shfl_xor(part, 8);
        float scale = sqKh * frsq_(fmaxf(o0f * o0f - part, 1e-12f));
        size_t orow = (size_t)(b * TT + qg[r]) * 1056 + h * 65;
        if (m == 0) O[orow] = (__bf16)(o0f * scale);
#pragma unroll
        for (int nt = 0; nt < 4; nt++) O[orow + 1 + nt * 16 + m] = (__bf16)(ov[nt] * scale);
    }
}

// ---------------------------------------------------------------- launch
extern "C" void kernel_launch(void* const* d_in, const int* in_sizes, int n_in,
                              void* d_out, int out_size, void* d_ws, size_t ws_size,
                              hipStream_t stream) {
    const float* x    = (const float*)d_in[0];
    const float* bc   = (const float*)d_in[1];
    const float* mc   = (const float*)d_in[2];
    const float* ac   = (const float*)d_in[3];
    const float* w_qkv = (const float*)d_in[4];
    const float* w_ap  = (const float*)d_in[5];
    const float* b_ap  = (const float*)d_in[6];
    const float* w_me  = (const float*)d_in[7];
    const float* b_me  = (const float*)d_in[8];
    const float* w_ms  = (const float*)d_in[9];
    const float* b_ms  = (const float*)d_in[10];
    const float* lnw  = (const float*)d_in[11];
    const float* lnb  = (const float*)d_in[12];
    float* out = (float*)d_out;
    float* ws  = (float*)d_ws;

    // workspace (floats), total ~94.4 MB — same layout as R5/R6.
    float* R      = ws;
    float* qkvbuf = R;
    float* X2     = R;
    __bf16* h_bf  = (__bf16*)(R + 4194304);
    float* p      = R + 12648448;
    __bf16* ln_bf = (__bf16*)p;  p += 2162688;   // M*1056 bf16
    __bf16* o_bf  = (__bf16*)p;  p += 2162688;   // M*1056 bf16
    __bf16* qkvT  = (__bf16*)p;  p += 1622016;   // 3072*1056 bf16
    __bf16* apT   = (__bf16*)p;  p += 540672;    // 1024*1056 bf16
    float*  meT_f = p;           p += 2164272;   // 4099*1056 bf16 (after flash)
    float*  msT_f = p;           p += 2113536;   // 1024*4128 bf16 (after flash)
    float* Qt = p;               p += 2 * HH * TT;
    float* Kt = p;               p += 2 * HH * TT;
    float* Vt = p;
    __bf16* meT = (__bf16*)meT_f;
    __bf16* msT = (__bf16*)msT_f;
    __bf16* Kb  = (__bf16*)meT_f;   // 32*2048*64 bf16 <= meT slot; dead before wt_k(meT)
    __bf16* Vtb = (__bf16*)msT_f;   // same size      <= msT slot; dead before wt_k(msT)

    // 0. weight transposes needed before flash
    wt_k<<<dim3(33, 96),  256, 0, stream>>>(w_qkv, 1025, 3072, qkvT, 1056);
    wt_k<<<dim3(33, 32),  256, 0, stream>>>(w_ap,  1040, 1024, apT,  1056);

    // 1. ln1 = block_norm(project(x)) -> bf16
    block_norm_bf_k<<<MM, 256, 0, stream>>>(x, 1024, ln_bf, lnw, lnb, bc);
    // 2. qkv = ln1 @ w_qkv -> fp32 (M,3072)
    mgemm_k<false, false, false, false><<<dim3(24, 32), 256, 0, stream>>>(
        ln_bf, 1056, qkvT, 1056, nullptr, nullptr, 0, qkvbuf, 3072, 3072, 1056);
    // 3a. RoPE (q in place fp32, Kb bf16) + q/k norms + o_bf pad
    rope_k<<<MM, 256, 0, stream>>>(qkvbuf, ac, Qt, Kt, Kb, o_bf);
    // 3b. V transpose -> Vtb bf16 + v norms
    vtrans_k<<<dim3(32, 32), 256, 0, stream>>>(qkvbuf, ac, Vtb, Vt);
    // 4. MFMA flash attention -> o_t bf16 (M,1056)
    flash_k<<<dim3(2 * HH, 32), 256, 0, stream>>>(qkvbuf, Kb, Vtb, Qt, Kt, Vt, ac, o_bf);
    // 0b. remaining weight transposes (into the slots Kb/Vtb just vacated)
    wt_k<<<dim3(33, 129), 256, 0, stream>>>(w_me,  1025, 4099, meT, 1056);
    wt_k<<<dim3(129, 32), 256, 0, stream>>>(w_ms,  4100, 1024, msT, 4128);
    // 5. lx2[...,1:] = x + o_t @ w_attn_proj + b -> X2 fp32
    mgemm64_k<true, false, true><<<dim3(16, 32), 256, 0, stream>>>(
        o_bf, 1056, apT, 1056, b_ap, x, 1024, X2, 1024, 1024, 1056);
    // 6. ln2 = block_norm(lx2) -> bf16
    block_norm_bf_k<<<MM, 256, 0, stream>>>(X2, 1024, ln_bf, lnw, lnb, bc);
    // 7. h = gelu(ln2 @ w_mlp_expand + b) -> bf16
    mgemm_k<true, true, false, true><<<dim3(33, 32), 256, 0, stream>>>(
        ln_bf, 1056, meT, 1056, b_me, nullptr, 0, (void*)(h_bf + 1), 4128, 4099, 1056);
    // 8. h x0 column + pad zero
    row_x0_bf_k<<<MM, 256, 0, stream>>>(h_bf, mc);
    // 9. out[...,1:] = lx2[...,1:] + h @ w_mlp_shrink + b
    mgemm64_k<true, false, true><<<dim3(16, 32), 256, 0, stream>>>(
        h_bf, 4128, msT, 4128, b_ms, X2, 1024, out + 1, 1025, 1024, 4128);
    // 10. out[...,0]
    row_x0_k<<<MM, 256, 0, stream>>>(out, 1025, 1024, bc);
}